// Round 16
// baseline (233.639 us; speedup 1.0000x reference)
//
#include <hip/hip_runtime.h>
#include <cstdint>
#include <cstddef>

// Problem constants
#define D_DIM 64
#define M_DIM 256
#define N_PTS 1024

typedef __attribute__((ext_vector_type(4))) float f32x4;
typedef __attribute__((ext_vector_type(2))) float f32x2;
typedef __attribute__((ext_vector_type(8))) short s16x8;

static __device__ __forceinline__ f32x2 pkfma(f32x2 a, f32x2 b, f32x2 c) {
#if __has_builtin(__builtin_elementwise_fma)
    return __builtin_elementwise_fma(a, b, c);
#else
    f32x2 r; r.x = fmaf(a.x, b.x, c.x); r.y = fmaf(a.y, b.y, c.y); return r;
#endif
}
static __device__ __forceinline__ f32x2 sp2(float s) {
    f32x2 r; r.x = s; r.y = s; return r;
}

static __device__ __forceinline__ float sp10f(float x) {
    // softplus(10x)/10, numerically stable, matches jax.nn.softplus
    float t = 10.f * x;
    return 0.1f * (fmaxf(t, 0.f) + log1pf(__expf(-fabsf(t))));
}

// packed branch-free tanh: 1 - 2/(exp2(x*2log2e)+1); single v_exp per lane
static __device__ __forceinline__ f32x2 ftanh2(f32x2 x) {
    f32x2 xs = x * sp2(2.88539008177793f);   // 2*log2(e)
    f32x2 e;
    e.x = __builtin_amdgcn_exp2f(xs.x);
    e.y = __builtin_amdgcn_exp2f(xs.y);
    f32x2 ep = e + sp2(1.f);
    f32x2 r;
    r.x = __builtin_amdgcn_rcpf(ep.x);
    r.y = __builtin_amdgcn_rcpf(ep.y);
    return pkfma(sp2(-2.f), r, sp2(1.f));
}

static __device__ __forceinline__ unsigned short f2bf(float x) {
    unsigned u = __float_as_uint(x);
    u = u + 0x7FFFu + ((u >> 16) & 1u);   // round-to-nearest-even
    return (unsigned short)(u >> 16);
}
static __device__ __forceinline__ float bf2f(unsigned short h) {
    return __uint_as_float(((unsigned)h) << 16);
}

// rne-hi / trunc-lo split of one fp32 -> (rounded-u32, lo-float-bits)
static __device__ __forceinline__ void split1(float x, unsigned& uh, unsigned& ul) {
    unsigned u = __float_as_uint(x);
    uh = u + 0x7FFFu + ((u >> 16) & 1u);               // rne in upper 16
    ul = __float_as_uint(x - __uint_as_float(uh & 0xFFFF0000u));  // exact tail
}

// map global level-group index g (0..61) -> (raw pointer, local g)
static __device__ __forceinline__ const float* map_g(int g, const float* a0, const float* a1,
                                                     const float* a2, const float* a3,
                                                     const float* a4, int& lg) {
    if (g < 32) { lg = g;      return a0; }
    if (g < 48) { lg = g - 32; return a1; }
    if (g < 56) { lg = g - 48; return a2; }
    if (g < 60) { lg = g - 56; return a3; }
    lg = g - 60; return a4;
}

// ---------------- fused prep: X-transpose + weight pack + HT transpose ---
// blocks 0..15: X transpose; 16..79: weight pack; 80..1071: HT transpose.
__global__ __launch_bounds__(256) void k_prep3(
    const float* __restrict__ X, const float* __restrict__ wf,
    const float* __restrict__ wm, const float* __restrict__ wl,
    const float* __restrict__ b1, const float* __restrict__ bm,
    const float* __restrict__ bl, const float* __restrict__ af,
    const float* __restrict__ am,
    const float* __restrict__ a0, const float* __restrict__ a1,
    const float* __restrict__ a2, const float* __restrict__ a3,
    const float* __restrict__ a4,
    float* __restrict__ Wpack, float* __restrict__ Xt,
    unsigned short* __restrict__ Anth, unsigned short* __restrict__ Antl) {
    __shared__ float tile[64][65];
    const int t = threadIdx.x;
    const int b = blockIdx.x;
    if (b < 16) {
        // transpose X: (N,D) -> Xt (D,N)
        const int n0 = b * 64;
#pragma unroll
        for (int i = 0; i < 4; i++) {
            const int f   = i * 256 + t;
            const int row = f >> 4;
            const int c4  = f & 15;
            float4 v = *(const float4*)(X + (size_t)(n0 + row) * 64 + c4 * 4);
            tile[row][c4 * 4 + 0] = v.x;
            tile[row][c4 * 4 + 1] = v.y;
            tile[row][c4 * 4 + 2] = v.z;
            tile[row][c4 * 4 + 3] = v.w;
        }
        __syncthreads();
#pragma unroll
        for (int i = 0; i < 4; i++) {
            const int f    = i * 256 + t;
            const int drow = f >> 4;
            const int c4   = f & 15;
            float4 v;
            v.x = tile[c4 * 4 + 0][drow];
            v.y = tile[c4 * 4 + 1][drow];
            v.z = tile[c4 * 4 + 2][drow];
            v.w = tile[c4 * 4 + 3][drow];
            *(float4*)(Xt + (size_t)drow * 1024 + n0 + c4 * 4) = v;
        }
        return;
    }
    if (b < 80) {
        // weight pack: record[dm] of 48 floats
        const int id = (b - 16) * 256 + t;  // 0..16383
        float r[48];
#pragma unroll
        for (int q = 0; q < 48; q++) r[q] = 0.f;
#pragma unroll
        for (int q = 0; q < 3; q++) {
            r[0 + q] = sp10f(wf[id * 3 + q]);
            r[3 + q] = b1[id * 3 + q];
            r[6 + q] = tanhf(af[id * 3 + q]);
            r[39 + q] = sp10f(wl[id * 3 + q]);
        }
#pragma unroll
        for (int l = 0; l < 2; l++) {
            const size_t b9 = ((size_t)l * 16384 + id) * 9;
            const size_t b3 = ((size_t)l * 16384 + id) * 3;
#pragma unroll
            for (int q = 0; q < 9; q++) r[9 + l * 15 + q] = sp10f(wm[b9 + q]);
#pragma unroll
            for (int q = 0; q < 3; q++) {
                r[18 + l * 15 + q] = bm[b3 + q];
                r[21 + l * 15 + q] = tanhf(am[b3 + q]);
            }
        }
        r[42] = bl[id];
        float4* o = (float4*)(Wpack + (size_t)id * 48);
#pragma unroll
        for (int q = 0; q < 12; q++) o[q] = ((float4*)r)[q];
        return;
    }
    // HT transpose + sp10 + bf16 hi/lo split: An_t[g][k][m]
    const int idx = b - 80;          // 0..991
    const int g   = idx >> 4;        // 0..61
    const int rr  = idx & 15;
    const int m0  = (rr & 3) * 64;
    const int k0  = (rr >> 2) * 64;
    int lg;
    const float* A  = map_g(g, a0, a1, a2, a3, a4, lg);
    const float* Ag = A + (size_t)lg * 65536;

#pragma unroll
    for (int i = 0; i < 4; i++) {
        const int f   = i * 256 + t;
        const int row = f >> 4;
        const int c4  = f & 15;
        float4 v = *(const float4*)(Ag + (size_t)(m0 + row) * 256 + k0 + c4 * 4);
        tile[row][c4 * 4 + 0] = v.x;
        tile[row][c4 * 4 + 1] = v.y;
        tile[row][c4 * 4 + 2] = v.z;
        tile[row][c4 * 4 + 3] = v.w;
    }
    __syncthreads();

#pragma unroll
    for (int i = 0; i < 4; i++) {
        const int f    = i * 256 + t;
        const int krow = f >> 4;
        const int c4   = f & 15;
        float v0 = sp10f(tile[c4 * 4 + 0][krow]);
        float v1 = sp10f(tile[c4 * 4 + 1][krow]);
        float v2 = sp10f(tile[c4 * 4 + 2][krow]);
        float v3 = sp10f(tile[c4 * 4 + 3][krow]);
        unsigned short h0 = f2bf(v0), h1 = f2bf(v1), h2 = f2bf(v2), h3 = f2bf(v3);
        ushort4 hi, lo;
        hi.x = h0; hi.y = h1; hi.z = h2; hi.w = h3;
        lo.x = f2bf(v0 - bf2f(h0));
        lo.y = f2bf(v1 - bf2f(h1));
        lo.z = f2bf(v2 - bf2f(h2));
        lo.w = f2bf(v3 - bf2f(h3));
        const size_t dst = (size_t)g * 65536 + (size_t)(k0 + krow) * 256 + m0 + c4 * 4;
        *(ushort4*)(Anth + dst) = hi;
        *(ushort4*)(Antl + dst) = lo;
    }
}

// column sums (over m) from transposed hi/lo rows.
__global__ void k_csum_t(const unsigned short* __restrict__ Anth,
                         const unsigned short* __restrict__ Antl,
                         float* __restrict__ csum) {
    const int g    = blockIdx.x;
    const int w    = threadIdx.x >> 6;
    const int lane = threadIdx.x & 63;
    const int k    = blockIdx.y * 4 + w;
    const size_t base = (size_t)g * 65536 + k * 256 + lane * 4;
    uint2 vh = *(const uint2*)(Anth + base);
    uint2 vl = *(const uint2*)(Antl + base);
    float s = 0.f;
    s += bf2f((unsigned short)(vh.x & 0xFFFFu)) + bf2f((unsigned short)(vh.x >> 16));
    s += bf2f((unsigned short)(vh.y & 0xFFFFu)) + bf2f((unsigned short)(vh.y >> 16));
    s += bf2f((unsigned short)(vl.x & 0xFFFFu)) + bf2f((unsigned short)(vl.x >> 16));
    s += bf2f((unsigned short)(vl.y & 0xFFFFu)) + bf2f((unsigned short)(vl.y >> 16));
    for (int off = 32; off > 0; off >>= 1) s += __shfl_down(s, off);
    if (lane == 0) csum[g * 256 + k] = s;
}

// ---------------- phase 1: wave = one (d,m) chain, 4 n per lane ----------
__global__ __launch_bounds__(512, 1) void k_phase1(
    const float* __restrict__ Xt, const float* __restrict__ Wpack,
    unsigned short* __restrict__ P0h, unsigned short* __restrict__ P0l) {
    __shared__ float sT[128][33];
    __shared__ float sXd[2][256];
    const int j  = blockIdx.x;        // d-pair
    const int mc = blockIdx.y;        // m-chunk of 32
    const int n0 = blockIdx.z * 256;  // n base
    const int t  = threadIdx.x;
    const int w    = __builtin_amdgcn_readfirstlane(t >> 6);
    const int lane = t & 63;

    sXd[t >> 8][t & 255] = Xt[(size_t)(2 * j + (t >> 8)) * 1024 + n0 + (t & 255)];
    __syncthreads();

    f32x2 x[2][2];
#pragma unroll
    for (int e = 0; e < 2; e++) {
        x[e][0].x = sXd[e][lane];       x[e][0].y = sXd[e][64 + lane];
        x[e][1].x = sXd[e][128 + lane]; x[e][1].y = sXd[e][192 + lane];
    }

    const f32x2 one2 = sp2(1.f);
    f32x2 pB[4];   // half-B products carried across phase 2

#pragma unroll 1
    for (int i = 0; i < 4; i++) {
        const int mm = w * 4 + i;          // 0..31 within this m-chunk
        const int m  = mc * 32 + mm;       // global m
        const float* __restrict__ rp0 =
            Wpack + (size_t)(((2 * j) << 8) + m) * 48;
        const float* __restrict__ rp1 = rp0 + 256 * 48;

        float W1a[2][3], B1a[2][3], T1a[2][3], Wm[2][2][9], Bm[2][2][3],
              Tm[2][2][3], Wla[2][3], Bla[2];
#pragma unroll
        for (int e = 0; e < 2; e++) {
            const float* __restrict__ rp = e ? rp1 : rp0;
#pragma unroll
            for (int r = 0; r < 3; r++) {
                W1a[e][r] = rp[r];
                B1a[e][r] = rp[3 + r];
                T1a[e][r] = rp[6 + r];
                Bm[e][0][r] = rp[18 + r];
                Tm[e][0][r] = rp[21 + r];
                Bm[e][1][r] = rp[33 + r];
                Tm[e][1][r] = rp[36 + r];
                Wla[e][r] = rp[39 + r];
            }
#pragma unroll
            for (int q = 0; q < 9; q++) {
                Wm[e][0][q] = rp[9 + q];
                Wm[e][1][q] = rp[24 + q];
            }
            Bla[e] = rp[42];
        }

        f32x2 phi[2][2][3], pd[2][2][3];
#pragma unroll
        for (int r = 0; r < 3; r++)
#pragma unroll
            for (int e = 0; e < 2; e++)
#pragma unroll
                for (int h = 0; h < 2; h++) {
                    f32x2 z  = pkfma(x[e][h], sp2(W1a[e][r]), sp2(B1a[e][r]));
                    f32x2 tz = ftanh2(z);
                    f32x2 ta = sp2(T1a[e][r]);
                    pd[e][h][r]  = sp2(W1a[e][r]) * pkfma(ta, pkfma(-tz, tz, one2), one2);
                    phi[e][h][r] = pkfma(tz, ta, z);
                }
#pragma unroll
        for (int l = 0; l < 2; l++) {
            f32x2 nphi[2][2][3], npd[2][2][3];
#pragma unroll
            for (int q = 0; q < 3; q++)
#pragma unroll
                for (int e = 0; e < 2; e++)
#pragma unroll
                    for (int h = 0; h < 2; h++) {
                        f32x2 z  = sp2(Bm[e][l][q]);
                        f32x2 dp = sp2(0.f);
#pragma unroll
                        for (int r = 0; r < 3; r++) {
                            f32x2 wv = sp2(Wm[e][l][r * 3 + q]);
                            z  = pkfma(phi[e][h][r], wv, z);
                            dp = pkfma(pd[e][h][r],  wv, dp);
                        }
                        f32x2 tz = ftanh2(z);
                        f32x2 ta = sp2(Tm[e][l][q]);
                        nphi[e][h][q] = pkfma(tz, ta, z);
                        npd[e][h][q]  = dp * pkfma(ta, pkfma(-tz, tz, one2), one2);
                    }
#pragma unroll
            for (int q = 0; q < 3; q++)
#pragma unroll
                for (int e = 0; e < 2; e++)
#pragma unroll
                    for (int h = 0; h < 2; h++) {
                        phi[e][h][q] = nphi[e][h][q];
                        pd[e][h][q]  = npd[e][h][q];
                    }
        }
        f32x2 prod[2][2];
#pragma unroll
        for (int e = 0; e < 2; e++)
#pragma unroll
            for (int h = 0; h < 2; h++) {
                f32x2 z  = sp2(Bla[e]);
                f32x2 dp = sp2(0.f);
#pragma unroll
                for (int r = 0; r < 3; r++) {
                    f32x2 wv = sp2(Wla[e][r]);
                    z  = pkfma(phi[e][h][r], wv, z);
                    dp = pkfma(pd[e][h][r],  wv, dp);
                }
                f32x2 zs = z * sp2(-1.4426950408889634f);
                f32x2 s;
                s.x = __builtin_amdgcn_rcpf(1.f + __builtin_amdgcn_exp2f(zs.x));
                s.y = __builtin_amdgcn_rcpf(1.f + __builtin_amdgcn_exp2f(zs.y));
                prod[e][h] = dp * s * (one2 - s);
            }
        f32x2 pA = prod[0][0] * prod[1][0];
        pB[i]    = prod[0][1] * prod[1][1];
        sT[lane][mm]      = pA.x;
        sT[64 + lane][mm] = pA.y;
    }
    __syncthreads();

    const size_t base = ((size_t)j * N_PTS + n0) * M_DIM + mc * 32;
#pragma unroll
    for (int it = 0; it < 2; it++) {
        const int idx = it * 512 + t;
        const int row = idx >> 3;
        const int c4  = idx & 7;
        float4 v;
        v.x = sT[row][c4 * 4 + 0];
        v.y = sT[row][c4 * 4 + 1];
        v.z = sT[row][c4 * 4 + 2];
        v.w = sT[row][c4 * 4 + 3];
        unsigned uh0, ul0, uh1, ul1, uh2, ul2, uh3, ul3;
        split1(v.x, uh0, ul0);
        split1(v.y, uh1, ul1);
        split1(v.z, uh2, ul2);
        split1(v.w, uh3, ul3);
        uint2 hp, lp;
        hp.x = __builtin_amdgcn_perm(uh1, uh0, 0x07060302u);
        hp.y = __builtin_amdgcn_perm(uh3, uh2, 0x07060302u);
        lp.x = __builtin_amdgcn_perm(ul1, ul0, 0x07060302u);
        lp.y = __builtin_amdgcn_perm(ul3, ul2, 0x07060302u);
        *(uint2*)(P0h + base + (size_t)row * M_DIM + c4 * 4) = hp;
        *(uint2*)(P0l + base + (size_t)row * M_DIM + c4 * 4) = lp;
    }
    __syncthreads();

#pragma unroll
    for (int i = 0; i < 4; i++) {
        const int mm = w * 4 + i;
        sT[lane][mm]      = pB[i].x;
        sT[64 + lane][mm] = pB[i].y;
    }
    __syncthreads();
    const size_t base2 = base + (size_t)128 * M_DIM;
#pragma unroll
    for (int it = 0; it < 2; it++) {
        const int idx = it * 512 + t;
        const int row = idx >> 3;
        const int c4  = idx & 7;
        float4 v;
        v.x = sT[row][c4 * 4 + 0];
        v.y = sT[row][c4 * 4 + 1];
        v.z = sT[row][c4 * 4 + 2];
        v.w = sT[row][c4 * 4 + 3];
        unsigned uh0, ul0, uh1, ul1, uh2, ul2, uh3, ul3;
        split1(v.x, uh0, ul0);
        split1(v.y, uh1, ul1);
        split1(v.z, uh2, ul2);
        split1(v.w, uh3, ul3);
        uint2 hp, lp;
        hp.x = __builtin_amdgcn_perm(uh1, uh0, 0x07060302u);
        hp.y = __builtin_amdgcn_perm(uh3, uh2, 0x07060302u);
        lp.x = __builtin_amdgcn_perm(ul1, ul0, 0x07060302u);
        lp.y = __builtin_amdgcn_perm(ul3, ul2, 0x07060302u);
        *(uint2*)(P0h + base2 + (size_t)row * M_DIM + c4 * 4) = hp;
        *(uint2*)(P0l + base2 + (size_t)row * M_DIM + c4 * 4) = lp;
    }
}

// ---------------- pair-product + bf16 split (between HT levels) ----------
// Qh/Ql[q] = split(G[2q] * G[2q+1]) elementwise. grid = npairs*128 blocks.
__global__ __launch_bounds__(256) void k_pair(const float* __restrict__ G,
                                              unsigned short* __restrict__ Qh,
                                              unsigned short* __restrict__ Ql) {
    const int i = blockIdx.x * 256 + threadIdx.x;
#pragma unroll
    for (int s = 0; s < 2; s++) {
        const int idx = i * 2 + s;        // float4 slot in output space
        const int q = idx >> 16;          // pair index (65536 float4/group)
        const int r = idx & 65535;
        const float4 a = *(const float4*)(G + ((size_t)(2 * q) << 18) + r * 4);
        const float4 b = *(const float4*)(G + ((size_t)(2 * q + 1) << 18) + r * 4);
        float4 v;
        v.x = a.x * b.x; v.y = a.y * b.y; v.z = a.z * b.z; v.w = a.w * b.w;
        unsigned uh0, ul0, uh1, ul1, uh2, ul2, uh3, ul3;
        split1(v.x, uh0, ul0);
        split1(v.y, uh1, ul1);
        split1(v.z, uh2, ul2);
        split1(v.w, uh3, ul3);
        uint2 hp, lp;
        hp.x = __builtin_amdgcn_perm(uh1, uh0, 0x07060302u);
        hp.y = __builtin_amdgcn_perm(uh3, uh2, 0x07060302u);
        lp.x = __builtin_amdgcn_perm(ul1, ul0, 0x07060302u);
        lp.y = __builtin_amdgcn_perm(ul3, ul2, 0x07060302u);
        *(uint2*)(Qh + ((size_t)q << 18) + r * 4) = hp;
        *(uint2*)(Ql + ((size_t)q << 18) + r * 4) = lp;
    }
}

// ---------------- LDS-free direct-fragment GEMM (all HT levels) ----------
// out[g][n][k] = (sum_m T[n][m] * An_t[k][m]) / csum[g][k]
// Every MFMA fragment is 16 contiguous bytes in global (T row-major [n][m],
// An transposed [k][m]) -> load fragments straight from L2. No LDS, no
// barriers; compiler pipelines loads across the unrolled m-loop.
// grid (16 n-tiles, 4 k-tiles, groups), 256 thr = 4 waves (2x2 of 32x32).
__global__ __launch_bounds__(256) void k_gdir(
    const unsigned short* __restrict__ Th, const unsigned short* __restrict__ Tl,
    const unsigned short* __restrict__ Bh, const unsigned short* __restrict__ Bl,
    const float* __restrict__ csum, float* __restrict__ Tout) {
    const int g  = blockIdx.z;
    const int n0 = blockIdx.x * 64;
    const int k0 = blockIdx.y * 64;
    const unsigned short* Thg = Th + ((size_t)g << 18);
    const unsigned short* Tlg = Tl + ((size_t)g << 18);
    const unsigned short* Bhg = Bh + ((size_t)g << 16);
    const unsigned short* Blg = Bl + ((size_t)g << 16);

    const int tid  = threadIdx.x;
    const int lane = tid & 63;
    const int w    = tid >> 6;
    const int wr   = w >> 1;
    const int wc   = w & 1;
    const int lr   = lane & 15;
    const int lk   = lane >> 4;

    const int rowA = n0 + wr * 32 + lr;   // + nt*16
    const int rowB = k0 + wc * 32 + lr;   // + kt*16

    f32x4 acc[2][2];
#pragma unroll
    for (int a = 0; a < 2; a++)
#pragma unroll
        for (int b = 0; b < 2; b++) acc[a][b] = (f32x4){0.f, 0.f, 0.f, 0.f};

#pragma unroll
    for (int kb = 0; kb < 256; kb += 32) {
        s16x8 ah[2], al[2], bh[2], bl[2];
#pragma unroll
        for (int nt = 0; nt < 2; nt++) {
            const size_t addr = (size_t)(rowA + nt * 16) * 256 + kb + lk * 8;
            ah[nt] = *(const s16x8*)(Thg + addr);
            al[nt] = *(const s16x8*)(Tlg + addr);
        }
#pragma unroll
        for (int kt = 0; kt < 2; kt++) {
            const size_t addr = (size_t)(rowB + kt * 16) * 256 + kb + lk * 8;
            bh[kt] = *(const s16x8*)(Bhg + addr);
            bl[kt] = *(const s16x8*)(Blg + addr);
        }
#pragma unroll
        for (int nt = 0; nt < 2; nt++)
#pragma unroll
            for (int kt = 0; kt < 2; kt++) {
                acc[nt][kt] = __builtin_amdgcn_mfma_f32_16x16x32_bf16(ah[nt], bh[kt], acc[nt][kt], 0, 0, 0);
                acc[nt][kt] = __builtin_amdgcn_mfma_f32_16x16x32_bf16(ah[nt], bl[kt], acc[nt][kt], 0, 0, 0);
                acc[nt][kt] = __builtin_amdgcn_mfma_f32_16x16x32_bf16(al[nt], bh[kt], acc[nt][kt], 0, 0, 0);
            }
    }

    float* Og = Tout + ((size_t)g << 18);
#pragma unroll
    for (int kt = 0; kt < 2; kt++) {
        const int col = k0 + wc * 32 + kt * 16 + lr;
        const float inv = 1.0f / csum[g * 256 + col];
#pragma unroll
        for (int nt = 0; nt < 2; nt++) {
            const int rbase = n0 + wr * 32 + nt * 16 + lk * 4;
#pragma unroll
            for (int r = 0; r < 4; r++)
                Og[(size_t)(rbase + r) * 256 + col] = acc[nt][kt][r] * inv;
        }
    }
}

// ---------------- level 5: pair-product + normalized dot -----------------
__global__ void k_l5(const float* __restrict__ Tin, const float* __restrict__ a5,
                     float* __restrict__ out) {
    const int n = blockIdx.x;
    const int m = threadIdx.x;
    __shared__ float sv[256], sw[256];
    float w = sp10f(a5[m]);
    float v = Tin[(size_t)n * 256 + m] * Tin[(size_t)(N_PTS + n) * 256 + m] * w;
    sv[m] = v;
    sw[m] = w;
    __syncthreads();
    for (int s = 128; s > 0; s >>= 1) {
        if (m < s) { sv[m] += sv[m + s]; sw[m] += sw[m + s]; }
        __syncthreads();
    }
    if (m == 0) out[n] = sv[0] / sw[0];
}

extern "C" void kernel_launch(void* const* d_in, const int* in_sizes, int n_in,
                              void* d_out, int out_size, void* d_ws, size_t ws_size,
                              hipStream_t stream) {
    const float* X  = (const float*)d_in[0];
    const float* wf = (const float*)d_in[1];
    const float* wm = (const float*)d_in[2];
    const float* wl = (const float*)d_in[3];
    const float* b1 = (const float*)d_in[4];
    const float* bm = (const float*)d_in[5];
    const float* bl = (const float*)d_in[6];
    const float* af = (const float*)d_in[7];
    const float* am = (const float*)d_in[8];
    const float* a0 = (const float*)d_in[9];
    const float* a1 = (const float*)d_in[10];
    const float* a2 = (const float*)d_in[11];
    const float* a3 = (const float*)d_in[12];
    const float* a4 = (const float*)d_in[13];
    const float* a5 = (const float*)d_in[14];
    float* out = (float*)d_out;

    float* ws    = (float*)d_ws;
    float* Wpack = ws;                                 // 786432 f
    float* Xt    = Wpack + 786432;                     // 65536 f
    float* csum  = Xt + 65536;                         // 15872 f
    unsigned short* Anth = (unsigned short*)(csum + 15872);  // 62*65536 us
    unsigned short* Antl = Anth + (size_t)62 * 65536;        // 62*65536 us
    unsigned short* P0h  = Antl + (size_t)62 * 65536;        // 32*262144 us
    unsigned short* P0l  = P0h + (size_t)32 * 262144;        // 32*262144 us
    float* Gbuf  = (float*)(P0l + (size_t)32 * 262144);      // 32*262144 f
    unsigned short* Qh   = (unsigned short*)(Gbuf + (size_t)32 * 262144); // 16*262144 us
    unsigned short* Ql   = Qh + (size_t)16 * 262144;         // 16*262144 us

    k_prep3<<<1072, 256, 0, stream>>>(X, wf, wm, wl, b1, bm, bl, af, am,
                                      a0, a1, a2, a3, a4, Wpack, Xt, Anth, Antl);
    k_csum_t<<<dim3(62, 64), 256, 0, stream>>>(Anth, Antl, csum);
    k_phase1<<<dim3(32, 8, 4), 512, 0, stream>>>(Xt, Wpack, P0h, P0l);

    // L0: 32 groups (presplit P0) -> Gbuf fp32
    k_gdir<<<dim3(16, 4, 32), 256, 0, stream>>>(P0h, P0l, Anth, Antl, csum, Gbuf);
    // L1: pair 32->16, GEMM
    k_pair<<<2048, 256, 0, stream>>>(Gbuf, Qh, Ql);
    k_gdir<<<dim3(16, 4, 16), 256, 0, stream>>>(Qh, Ql, Anth + (size_t)32 * 65536,
                                                Antl + (size_t)32 * 65536,
                                                csum + 32 * 256, Gbuf);
    // L2: pair 16->8, GEMM
    k_pair<<<1024, 256, 0, stream>>>(Gbuf, Qh, Ql);
    k_gdir<<<dim3(16, 4, 8), 256, 0, stream>>>(Qh, Ql, Anth + (size_t)48 * 65536,
                                               Antl + (size_t)48 * 65536,
                                               csum + 48 * 256, Gbuf);
    // L3: pair 8->4, GEMM
    k_pair<<<512, 256, 0, stream>>>(Gbuf, Qh, Ql);
    k_gdir<<<dim3(16, 4, 4), 256, 0, stream>>>(Qh, Ql, Anth + (size_t)56 * 65536,
                                               Antl + (size_t)56 * 65536,
                                               csum + 56 * 256, Gbuf);
    // L4: pair 4->2, GEMM
    k_pair<<<256, 256, 0, stream>>>(Gbuf, Qh, Ql);
    k_gdir<<<dim3(16, 4, 2), 256, 0, stream>>>(Qh, Ql, Anth + (size_t)60 * 65536,
                                               Antl + (size_t)60 * 65536,
                                               csum + 60 * 256, Gbuf);
    // level 5
    k_l5<<<N_PTS, 256, 0, stream>>>(Gbuf, a5, out);
}

// Round 17
// 162.777 us; speedup vs baseline: 1.4353x; 1.4353x over previous
//
#include <hip/hip_runtime.h>
#include <cstdint>
#include <cstddef>

// Problem constants
#define D_DIM 64
#define M_DIM 256
#define N_PTS 1024

typedef __attribute__((ext_vector_type(4))) float f32x4;
typedef __attribute__((ext_vector_type(2))) float f32x2;
typedef __attribute__((ext_vector_type(8))) short s16x8;

static __device__ __forceinline__ f32x2 pkfma(f32x2 a, f32x2 b, f32x2 c) {
#if __has_builtin(__builtin_elementwise_fma)
    return __builtin_elementwise_fma(a, b, c);
#else
    f32x2 r; r.x = fmaf(a.x, b.x, c.x); r.y = fmaf(a.y, b.y, c.y); return r;
#endif
}
static __device__ __forceinline__ f32x2 sp2(float s) {
    f32x2 r; r.x = s; r.y = s; return r;
}

static __device__ __forceinline__ float sp10f(float x) {
    // softplus(10x)/10, numerically stable, matches jax.nn.softplus
    float t = 10.f * x;
    return 0.1f * (fmaxf(t, 0.f) + log1pf(__expf(-fabsf(t))));
}

// packed branch-free tanh: 1 - 2/(exp2(x*2log2e)+1); single v_exp per lane
static __device__ __forceinline__ f32x2 ftanh2(f32x2 x) {
    f32x2 xs = x * sp2(2.88539008177793f);   // 2*log2(e)
    f32x2 e;
    e.x = __builtin_amdgcn_exp2f(xs.x);
    e.y = __builtin_amdgcn_exp2f(xs.y);
    f32x2 ep = e + sp2(1.f);
    f32x2 r;
    r.x = __builtin_amdgcn_rcpf(ep.x);
    r.y = __builtin_amdgcn_rcpf(ep.y);
    return pkfma(sp2(-2.f), r, sp2(1.f));
}

static __device__ __forceinline__ unsigned short f2bf(float x) {
    unsigned u = __float_as_uint(x);
    u = u + 0x7FFFu + ((u >> 16) & 1u);   // round-to-nearest-even
    return (unsigned short)(u >> 16);
}
static __device__ __forceinline__ float bf2f(unsigned short h) {
    return __uint_as_float(((unsigned)h) << 16);
}

// rne-hi / trunc-lo split of one fp32 -> (rounded-u32, lo-float-bits)
static __device__ __forceinline__ void split1(float x, unsigned& uh, unsigned& ul) {
    unsigned u = __float_as_uint(x);
    uh = u + 0x7FFFu + ((u >> 16) & 1u);               // rne in upper 16
    ul = __float_as_uint(x - __uint_as_float(uh & 0xFFFF0000u));  // exact tail
}

// map global level-group index g (0..61) -> (raw pointer, local g)
static __device__ __forceinline__ const float* map_g(int g, const float* a0, const float* a1,
                                                     const float* a2, const float* a3,
                                                     const float* a4, int& lg) {
    if (g < 32) { lg = g;      return a0; }
    if (g < 48) { lg = g - 32; return a1; }
    if (g < 56) { lg = g - 48; return a2; }
    if (g < 60) { lg = g - 56; return a3; }
    lg = g - 60; return a4;
}

// ---------------- fused prep: X-transpose + weight pack + HT transpose ---
// blocks 0..15: X transpose; 16..79: weight pack; 80..1071: HT transpose.
__global__ __launch_bounds__(256) void k_prep3(
    const float* __restrict__ X, const float* __restrict__ wf,
    const float* __restrict__ wm, const float* __restrict__ wl,
    const float* __restrict__ b1, const float* __restrict__ bm,
    const float* __restrict__ bl, const float* __restrict__ af,
    const float* __restrict__ am,
    const float* __restrict__ a0, const float* __restrict__ a1,
    const float* __restrict__ a2, const float* __restrict__ a3,
    const float* __restrict__ a4,
    float* __restrict__ Wpack, float* __restrict__ Xt,
    unsigned short* __restrict__ Anth, unsigned short* __restrict__ Antl) {
    __shared__ float tile[64][65];
    const int t = threadIdx.x;
    const int b = blockIdx.x;
    if (b < 16) {
        // transpose X: (N,D) -> Xt (D,N)
        const int n0 = b * 64;
#pragma unroll
        for (int i = 0; i < 4; i++) {
            const int f   = i * 256 + t;
            const int row = f >> 4;
            const int c4  = f & 15;
            float4 v = *(const float4*)(X + (size_t)(n0 + row) * 64 + c4 * 4);
            tile[row][c4 * 4 + 0] = v.x;
            tile[row][c4 * 4 + 1] = v.y;
            tile[row][c4 * 4 + 2] = v.z;
            tile[row][c4 * 4 + 3] = v.w;
        }
        __syncthreads();
#pragma unroll
        for (int i = 0; i < 4; i++) {
            const int f    = i * 256 + t;
            const int drow = f >> 4;
            const int c4   = f & 15;
            float4 v;
            v.x = tile[c4 * 4 + 0][drow];
            v.y = tile[c4 * 4 + 1][drow];
            v.z = tile[c4 * 4 + 2][drow];
            v.w = tile[c4 * 4 + 3][drow];
            *(float4*)(Xt + (size_t)drow * 1024 + n0 + c4 * 4) = v;
        }
        return;
    }
    if (b < 80) {
        // weight pack: record[dm] of 48 floats
        const int id = (b - 16) * 256 + t;  // 0..16383
        float r[48];
#pragma unroll
        for (int q = 0; q < 48; q++) r[q] = 0.f;
#pragma unroll
        for (int q = 0; q < 3; q++) {
            r[0 + q] = sp10f(wf[id * 3 + q]);
            r[3 + q] = b1[id * 3 + q];
            r[6 + q] = tanhf(af[id * 3 + q]);
            r[39 + q] = sp10f(wl[id * 3 + q]);
        }
#pragma unroll
        for (int l = 0; l < 2; l++) {
            const size_t b9 = ((size_t)l * 16384 + id) * 9;
            const size_t b3 = ((size_t)l * 16384 + id) * 3;
#pragma unroll
            for (int q = 0; q < 9; q++) r[9 + l * 15 + q] = sp10f(wm[b9 + q]);
#pragma unroll
            for (int q = 0; q < 3; q++) {
                r[18 + l * 15 + q] = bm[b3 + q];
                r[21 + l * 15 + q] = tanhf(am[b3 + q]);
            }
        }
        r[42] = bl[id];
        float4* o = (float4*)(Wpack + (size_t)id * 48);
#pragma unroll
        for (int q = 0; q < 12; q++) o[q] = ((float4*)r)[q];
        return;
    }
    // HT transpose + sp10 + bf16 hi/lo split: An_t[g][k][m]
    const int idx = b - 80;          // 0..991
    const int g   = idx >> 4;        // 0..61
    const int rr  = idx & 15;
    const int m0  = (rr & 3) * 64;
    const int k0  = (rr >> 2) * 64;
    int lg;
    const float* A  = map_g(g, a0, a1, a2, a3, a4, lg);
    const float* Ag = A + (size_t)lg * 65536;

#pragma unroll
    for (int i = 0; i < 4; i++) {
        const int f   = i * 256 + t;
        const int row = f >> 4;
        const int c4  = f & 15;
        float4 v = *(const float4*)(Ag + (size_t)(m0 + row) * 256 + k0 + c4 * 4);
        tile[row][c4 * 4 + 0] = v.x;
        tile[row][c4 * 4 + 1] = v.y;
        tile[row][c4 * 4 + 2] = v.z;
        tile[row][c4 * 4 + 3] = v.w;
    }
    __syncthreads();

#pragma unroll
    for (int i = 0; i < 4; i++) {
        const int f    = i * 256 + t;
        const int krow = f >> 4;
        const int c4   = f & 15;
        float v0 = sp10f(tile[c4 * 4 + 0][krow]);
        float v1 = sp10f(tile[c4 * 4 + 1][krow]);
        float v2 = sp10f(tile[c4 * 4 + 2][krow]);
        float v3 = sp10f(tile[c4 * 4 + 3][krow]);
        unsigned short h0 = f2bf(v0), h1 = f2bf(v1), h2 = f2bf(v2), h3 = f2bf(v3);
        ushort4 hi, lo;
        hi.x = h0; hi.y = h1; hi.z = h2; hi.w = h3;
        lo.x = f2bf(v0 - bf2f(h0));
        lo.y = f2bf(v1 - bf2f(h1));
        lo.z = f2bf(v2 - bf2f(h2));
        lo.w = f2bf(v3 - bf2f(h3));
        const size_t dst = (size_t)g * 65536 + (size_t)(k0 + krow) * 256 + m0 + c4 * 4;
        *(ushort4*)(Anth + dst) = hi;
        *(ushort4*)(Antl + dst) = lo;
    }
}

// column sums (over m) from transposed hi/lo rows.
__global__ void k_csum_t(const unsigned short* __restrict__ Anth,
                         const unsigned short* __restrict__ Antl,
                         float* __restrict__ csum) {
    const int g    = blockIdx.x;
    const int w    = threadIdx.x >> 6;
    const int lane = threadIdx.x & 63;
    const int k    = blockIdx.y * 4 + w;
    const size_t base = (size_t)g * 65536 + k * 256 + lane * 4;
    uint2 vh = *(const uint2*)(Anth + base);
    uint2 vl = *(const uint2*)(Antl + base);
    float s = 0.f;
    s += bf2f((unsigned short)(vh.x & 0xFFFFu)) + bf2f((unsigned short)(vh.x >> 16));
    s += bf2f((unsigned short)(vh.y & 0xFFFFu)) + bf2f((unsigned short)(vh.y >> 16));
    s += bf2f((unsigned short)(vl.x & 0xFFFFu)) + bf2f((unsigned short)(vl.x >> 16));
    s += bf2f((unsigned short)(vl.y & 0xFFFFu)) + bf2f((unsigned short)(vl.y >> 16));
    for (int off = 32; off > 0; off >>= 1) s += __shfl_down(s, off);
    if (lane == 0) csum[g * 256 + k] = s;
}

// ---------------- phase 1: wave = one (d,m) chain, 2 n per lane (packed) -
// (round-14 configuration: m-split, 16.9 KB LDS, unroll 2)
__global__ __launch_bounds__(512, 1) void k_phase1(
    const float* __restrict__ Xt, const float* __restrict__ Wpack,
    unsigned short* __restrict__ P0h, unsigned short* __restrict__ P0l) {
    __shared__ float sT[128][33];
    __shared__ float sXd[2][128];
    const int j  = blockIdx.x;        // d-pair
    const int mc = blockIdx.y;        // m-chunk of 32
    const int n0 = blockIdx.z * 128;  // n base
    const int t  = threadIdx.x;
    const int w    = __builtin_amdgcn_readfirstlane(t >> 6);
    const int lane = t & 63;

    if (t < 256)
        sXd[t >> 7][t & 127] = Xt[(size_t)(2 * j + (t >> 7)) * 1024 + n0 + (t & 127)];
    __syncthreads();

    f32x2 xe0, xe1;
    xe0.x = sXd[0][lane]; xe0.y = sXd[0][64 + lane];
    xe1.x = sXd[1][lane]; xe1.y = sXd[1][64 + lane];

    const f32x2 one2 = sp2(1.f);
    f32x2 p0;

#pragma unroll 2
    for (int it = 0; it < 8; it++) {
        const int i  = it >> 1;
        const int e  = it & 1;
        const int mm = w * 4 + i;          // 0..31 within this m-chunk
        const int m  = mc * 32 + mm;       // global m
        const float* __restrict__ rp =
            Wpack + (size_t)(((2 * j + e) << 8) + m) * 48;
        float W1a[3], B1a[3], T1a[3], Wm[2][9], Bm[2][3], Tm[2][3], Wla[3];
#pragma unroll
        for (int r = 0; r < 3; r++) {
            W1a[r] = rp[r];
            B1a[r] = rp[3 + r];
            T1a[r] = rp[6 + r];
            Bm[0][r] = rp[18 + r];
            Tm[0][r] = rp[21 + r];
            Bm[1][r] = rp[33 + r];
            Tm[1][r] = rp[36 + r];
            Wla[r] = rp[39 + r];
        }
#pragma unroll
        for (int q = 0; q < 9; q++) {
            Wm[0][q] = rp[9 + q];
            Wm[1][q] = rp[24 + q];
        }
        const float Bla = rp[42];

        const f32x2 x = e ? xe1 : xe0;
        f32x2 phi[3], pd[3];
#pragma unroll
        for (int r = 0; r < 3; r++) {
            f32x2 z  = pkfma(x, sp2(W1a[r]), sp2(B1a[r]));
            f32x2 tz = ftanh2(z);
            f32x2 ta = sp2(T1a[r]);
            pd[r]  = sp2(W1a[r]) * pkfma(ta, pkfma(-tz, tz, one2), one2);
            phi[r] = pkfma(tz, ta, z);
        }
#pragma unroll
        for (int l = 0; l < 2; l++) {
            f32x2 nphi[3], npd[3];
#pragma unroll
            for (int q = 0; q < 3; q++) {
                f32x2 z  = sp2(Bm[l][q]);
                f32x2 dp = sp2(0.f);
#pragma unroll
                for (int r = 0; r < 3; r++) {
                    f32x2 wv = sp2(Wm[l][r * 3 + q]);
                    z  = pkfma(phi[r], wv, z);
                    dp = pkfma(pd[r],  wv, dp);
                }
                f32x2 tz = ftanh2(z);
                f32x2 ta = sp2(Tm[l][q]);
                nphi[q] = pkfma(tz, ta, z);
                npd[q]  = dp * pkfma(ta, pkfma(-tz, tz, one2), one2);
            }
#pragma unroll
            for (int q = 0; q < 3; q++) { phi[q] = nphi[q]; pd[q] = npd[q]; }
        }
        f32x2 z  = sp2(Bla);
        f32x2 dp = sp2(0.f);
#pragma unroll
        for (int r = 0; r < 3; r++) {
            f32x2 wv = sp2(Wla[r]);
            z  = pkfma(phi[r], wv, z);
            dp = pkfma(pd[r],  wv, dp);
        }
        // sigmoid via single exp2 per component
        f32x2 zs = z * sp2(-1.4426950408889634f);
        f32x2 s;
        s.x = __builtin_amdgcn_rcpf(1.f + __builtin_amdgcn_exp2f(zs.x));
        s.y = __builtin_amdgcn_rcpf(1.f + __builtin_amdgcn_exp2f(zs.y));
        f32x2 prod = dp * s * (one2 - s);
        if (e == 0) {
            p0 = prod;
        } else {
            sT[lane][mm]      = p0.x * prod.x;
            sT[64 + lane][mm] = p0.y * prod.y;
        }
    }
    __syncthreads();

    // cooperative coalesced write: sT (128 n x 32 m) -> P0h/P0l[j][n][m]
    const size_t base = ((size_t)j * N_PTS + n0) * M_DIM + mc * 32;
#pragma unroll
    for (int it = 0; it < 2; it++) {
        const int idx = it * 512 + t;   // 1024 float4 slots
        const int row = idx >> 3;       // n local 0..127
        const int c4  = idx & 7;        // m float4 (8 per row)
        float4 v;
        v.x = sT[row][c4 * 4 + 0];
        v.y = sT[row][c4 * 4 + 1];
        v.z = sT[row][c4 * 4 + 2];
        v.w = sT[row][c4 * 4 + 3];
        unsigned uh0, ul0, uh1, ul1, uh2, ul2, uh3, ul3;
        split1(v.x, uh0, ul0);
        split1(v.y, uh1, ul1);
        split1(v.z, uh2, ul2);
        split1(v.w, uh3, ul3);
        uint2 hp, lp;
        hp.x = __builtin_amdgcn_perm(uh1, uh0, 0x07060302u);
        hp.y = __builtin_amdgcn_perm(uh3, uh2, 0x07060302u);
        lp.x = __builtin_amdgcn_perm(ul1, ul0, 0x07060302u);
        lp.y = __builtin_amdgcn_perm(ul3, ul2, 0x07060302u);
        *(uint2*)(P0h + base + (size_t)row * M_DIM + c4 * 4) = hp;
        *(uint2*)(P0l + base + (size_t)row * M_DIM + c4 * 4) = lp;
    }
}

// ---------------- pair-product + bf16 split (between HT levels) ----------
// Qh/Ql[q] = split(G[2q] * G[2q+1]) elementwise. grid = npairs*128 blocks.
__global__ __launch_bounds__(256) void k_pair(const float* __restrict__ G,
                                              unsigned short* __restrict__ Qh,
                                              unsigned short* __restrict__ Ql) {
    const int i = blockIdx.x * 256 + threadIdx.x;
#pragma unroll
    for (int s = 0; s < 2; s++) {
        const int idx = i * 2 + s;        // float4 slot in output space
        const int q = idx >> 16;          // pair index (65536 float4/group)
        const int r = idx & 65535;
        const float4 a = *(const float4*)(G + ((size_t)(2 * q) << 18) + r * 4);
        const float4 b = *(const float4*)(G + ((size_t)(2 * q + 1) << 18) + r * 4);
        float4 v;
        v.x = a.x * b.x; v.y = a.y * b.y; v.z = a.z * b.z; v.w = a.w * b.w;
        unsigned uh0, ul0, uh1, ul1, uh2, ul2, uh3, ul3;
        split1(v.x, uh0, ul0);
        split1(v.y, uh1, ul1);
        split1(v.z, uh2, ul2);
        split1(v.w, uh3, ul3);
        uint2 hp, lp;
        hp.x = __builtin_amdgcn_perm(uh1, uh0, 0x07060302u);
        hp.y = __builtin_amdgcn_perm(uh3, uh2, 0x07060302u);
        lp.x = __builtin_amdgcn_perm(ul1, ul0, 0x07060302u);
        lp.y = __builtin_amdgcn_perm(ul3, ul2, 0x07060302u);
        *(uint2*)(Qh + ((size_t)q << 18) + r * 4) = hp;
        *(uint2*)(Ql + ((size_t)q << 18) + r * 4) = lp;
    }
}

#define LDST64 72  // LDS row stride in bf16 elems (64 + 8 pad = 144 B)

// ---------------- all HT levels: 64x64 GEMM, BK=64, presplit pure copy ---
__global__ __launch_bounds__(256, 4) void k_g64ps(
    const unsigned short* __restrict__ Th, const unsigned short* __restrict__ Tl,
    const unsigned short* __restrict__ Bh, const unsigned short* __restrict__ Bl,
    const float* __restrict__ csum, float* __restrict__ Tout) {
    __shared__ unsigned short sAh[64 * LDST64];
    __shared__ unsigned short sAl[64 * LDST64];
    __shared__ unsigned short sBh[64 * LDST64];
    __shared__ unsigned short sBl[64 * LDST64];

    const int g  = blockIdx.z;
    const int n0 = blockIdx.x * 64;
    const int k0 = blockIdx.y * 64;
    const unsigned short* Thg = Th + ((size_t)g << 18);
    const unsigned short* Tlg = Tl + ((size_t)g << 18);
    const unsigned short* Bhg = Bh + ((size_t)g << 16);
    const unsigned short* Blg = Bl + ((size_t)g << 16);

    const int tid  = threadIdx.x;
    const int lane = tid & 63;
    const int w    = tid >> 6;
    const int wr   = w >> 1;
    const int wc   = w & 1;
    const int lr   = lane & 15;
    const int lk   = lane >> 4;

    f32x4 acc[2][2];
#pragma unroll
    for (int a = 0; a < 2; a++)
#pragma unroll
        for (int b = 0; b < 2; b++) acc[a][b] = (f32x4){0.f, 0.f, 0.f, 0.f};

    for (int kb = 0; kb < 256; kb += 64) {
#pragma unroll
        for (int i = 0; i < 2; i++) {
            const int idx = i * 256 + tid;   // 512 uint4 slots per buffer
            const int row = idx >> 3;        // 0..63
            const int seg = idx & 7;         // 8 ushorts each
            const size_t srcA = (size_t)(n0 + row) * 256 + kb + seg * 8;
            const size_t srcB = (size_t)(k0 + row) * 256 + kb + seg * 8;
            *(uint4*)&sAh[row * LDST64 + seg * 8] = *(const uint4*)(Thg + srcA);
            *(uint4*)&sAl[row * LDST64 + seg * 8] = *(const uint4*)(Tlg + srcA);
            *(uint4*)&sBh[row * LDST64 + seg * 8] = *(const uint4*)(Bhg + srcB);
            *(uint4*)&sBl[row * LDST64 + seg * 8] = *(const uint4*)(Blg + srcB);
        }
        __syncthreads();

        s16x8 ah[2][2], al[2][2], bh[2][2], bl[2][2];
#pragma unroll
        for (int nt = 0; nt < 2; nt++)
#pragma unroll
            for (int ks = 0; ks < 2; ks++) {
                const int off = (wr * 32 + nt * 16 + lr) * LDST64 + ks * 32 + lk * 8;
                ah[nt][ks] = *(const s16x8*)&sAh[off];
                al[nt][ks] = *(const s16x8*)&sAl[off];
            }
#pragma unroll
        for (int kt = 0; kt < 2; kt++)
#pragma unroll
            for (int ks = 0; ks < 2; ks++) {
                const int off = (wc * 32 + kt * 16 + lr) * LDST64 + ks * 32 + lk * 8;
                bh[kt][ks] = *(const s16x8*)&sBh[off];
                bl[kt][ks] = *(const s16x8*)&sBl[off];
            }
#pragma unroll
        for (int ks = 0; ks < 2; ks++)
#pragma unroll
            for (int nt = 0; nt < 2; nt++)
#pragma unroll
                for (int kt = 0; kt < 2; kt++) {
                    acc[nt][kt] = __builtin_amdgcn_mfma_f32_16x16x32_bf16(ah[nt][ks], bh[kt][ks], acc[nt][kt], 0, 0, 0);
                    acc[nt][kt] = __builtin_amdgcn_mfma_f32_16x16x32_bf16(ah[nt][ks], bl[kt][ks], acc[nt][kt], 0, 0, 0);
                    acc[nt][kt] = __builtin_amdgcn_mfma_f32_16x16x32_bf16(al[nt][ks], bh[kt][ks], acc[nt][kt], 0, 0, 0);
                }
        __syncthreads();
    }

    float* Og = Tout + ((size_t)g << 18);
#pragma unroll
    for (int kt = 0; kt < 2; kt++) {
        const int col = k0 + wc * 32 + kt * 16 + lr;
        const float inv = 1.0f / csum[g * 256 + col];
#pragma unroll
        for (int nt = 0; nt < 2; nt++) {
            const int rbase = n0 + wr * 32 + nt * 16 + lk * 4;
#pragma unroll
            for (int r = 0; r < 4; r++)
                Og[(size_t)(rbase + r) * 256 + col] = acc[nt][kt][r] * inv;
        }
    }
}

// ---------------- level 5: pair-product + normalized dot -----------------
__global__ void k_l5(const float* __restrict__ Tin, const float* __restrict__ a5,
                     float* __restrict__ out) {
    const int n = blockIdx.x;
    const int m = threadIdx.x;
    __shared__ float sv[256], sw[256];
    float w = sp10f(a5[m]);
    float v = Tin[(size_t)n * 256 + m] * Tin[(size_t)(N_PTS + n) * 256 + m] * w;
    sv[m] = v;
    sw[m] = w;
    __syncthreads();
    for (int s = 128; s > 0; s >>= 1) {
        if (m < s) { sv[m] += sv[m + s]; sw[m] += sw[m + s]; }
        __syncthreads();
    }
    if (m == 0) out[n] = sv[0] / sw[0];
}

extern "C" void kernel_launch(void* const* d_in, const int* in_sizes, int n_in,
                              void* d_out, int out_size, void* d_ws, size_t ws_size,
                              hipStream_t stream) {
    const float* X  = (const float*)d_in[0];
    const float* wf = (const float*)d_in[1];
    const float* wm = (const float*)d_in[2];
    const float* wl = (const float*)d_in[3];
    const float* b1 = (const float*)d_in[4];
    const float* bm = (const float*)d_in[5];
    const float* bl = (const float*)d_in[6];
    const float* af = (const float*)d_in[7];
    const float* am = (const float*)d_in[8];
    const float* a0 = (const float*)d_in[9];
    const float* a1 = (const float*)d_in[10];
    const float* a2 = (const float*)d_in[11];
    const float* a3 = (const float*)d_in[12];
    const float* a4 = (const float*)d_in[13];
    const float* a5 = (const float*)d_in[14];
    float* out = (float*)d_out;

    float* ws    = (float*)d_ws;
    float* Wpack = ws;                                 // 786432 f
    float* Xt    = Wpack + 786432;                     // 65536 f
    float* csum  = Xt + 65536;                         // 15872 f
    unsigned short* Anth = (unsigned short*)(csum + 15872);  // 62*65536 us
    unsigned short* Antl = Anth + (size_t)62 * 65536;        // 62*65536 us
    unsigned short* P0h  = Antl + (size_t)62 * 65536;        // 32*262144 us
    unsigned short* P0l  = P0h + (size_t)32 * 262144;        // 32*262144 us
    float* Gbuf  = (float*)(P0l + (size_t)32 * 262144);      // 32*262144 f
    unsigned short* Qh   = (unsigned short*)(Gbuf + (size_t)32 * 262144); // 16*262144 us
    unsigned short* Ql   = Qh + (size_t)16 * 262144;         // 16*262144 us

    k_prep3<<<1072, 256, 0, stream>>>(X, wf, wm, wl, b1, bm, bl, af, am,
                                      a0, a1, a2, a3, a4, Wpack, Xt, Anth, Antl);
    k_csum_t<<<dim3(62, 64), 256, 0, stream>>>(Anth, Antl, csum);
    k_phase1<<<dim3(32, 8, 8), 512, 0, stream>>>(Xt, Wpack, P0h, P0l);

    // L0: 32 groups (presplit P0) -> Gbuf fp32
    k_g64ps<<<dim3(16, 4, 32), 256, 0, stream>>>(P0h, P0l, Anth, Antl, csum, Gbuf);
    // L1: pair 32->16 (presplit), GEMM
    k_pair<<<2048, 256, 0, stream>>>(Gbuf, Qh, Ql);
    k_g64ps<<<dim3(16, 4, 16), 256, 0, stream>>>(Qh, Ql, Anth + (size_t)32 * 65536,
                                                 Antl + (size_t)32 * 65536,
                                                 csum + 32 * 256, Gbuf);
    // L2: pair 16->8, GEMM
    k_pair<<<1024, 256, 0, stream>>>(Gbuf, Qh, Ql);
    k_g64ps<<<dim3(16, 4, 8), 256, 0, stream>>>(Qh, Ql, Anth + (size_t)48 * 65536,
                                                Antl + (size_t)48 * 65536,
                                                csum + 48 * 256, Gbuf);
    // L3: pair 8->4, GEMM
    k_pair<<<512, 256, 0, stream>>>(Gbuf, Qh, Ql);
    k_g64ps<<<dim3(16, 4, 4), 256, 0, stream>>>(Qh, Ql, Anth + (size_t)56 * 65536,
                                                Antl + (size_t)56 * 65536,
                                                csum + 56 * 256, Gbuf);
    // L4: pair 4->2, GEMM
    k_pair<<<256, 256, 0, stream>>>(Gbuf, Qh, Ql);
    k_g64ps<<<dim3(16, 4, 2), 256, 0, stream>>>(Qh, Ql, Anth + (size_t)60 * 65536,
                                                Antl + (size_t)60 * 65536,
                                                csum + 60 * 256, Gbuf);
    // level 5
    k_l5<<<N_PTS, 256, 0, stream>>>(Gbuf, a5, out);
}

// Round 18
// 162.522 us; speedup vs baseline: 1.4376x; 1.0016x over previous
//
#include <hip/hip_runtime.h>
#include <cstdint>
#include <cstddef>

// Problem constants
#define D_DIM 64
#define M_DIM 256
#define N_PTS 1024

typedef __attribute__((ext_vector_type(4))) float f32x4;
typedef __attribute__((ext_vector_type(2))) float f32x2;
typedef __attribute__((ext_vector_type(8))) short s16x8;

static __device__ __forceinline__ f32x2 pkfma(f32x2 a, f32x2 b, f32x2 c) {
#if __has_builtin(__builtin_elementwise_fma)
    return __builtin_elementwise_fma(a, b, c);
#else
    f32x2 r; r.x = fmaf(a.x, b.x, c.x); r.y = fmaf(a.y, b.y, c.y); return r;
#endif
}
static __device__ __forceinline__ f32x2 sp2(float s) {
    f32x2 r; r.x = s; r.y = s; return r;
}

static __device__ __forceinline__ float sp10f(float x) {
    // softplus(10x)/10, numerically stable, matches jax.nn.softplus
    float t = 10.f * x;
    return 0.1f * (fmaxf(t, 0.f) + log1pf(__expf(-fabsf(t))));
}

// packed branch-free tanh: 1 - 2/(exp2(x*2log2e)+1); single v_exp per lane
static __device__ __forceinline__ f32x2 ftanh2(f32x2 x) {
    f32x2 xs = x * sp2(2.88539008177793f);   // 2*log2(e)
    f32x2 e;
    e.x = __builtin_amdgcn_exp2f(xs.x);
    e.y = __builtin_amdgcn_exp2f(xs.y);
    f32x2 ep = e + sp2(1.f);
    f32x2 r;
    r.x = __builtin_amdgcn_rcpf(ep.x);
    r.y = __builtin_amdgcn_rcpf(ep.y);
    return pkfma(sp2(-2.f), r, sp2(1.f));
}

static __device__ __forceinline__ unsigned short f2bf(float x) {
    unsigned u = __float_as_uint(x);
    u = u + 0x7FFFu + ((u >> 16) & 1u);   // round-to-nearest-even
    return (unsigned short)(u >> 16);
}
static __device__ __forceinline__ float bf2f(unsigned short h) {
    return __uint_as_float(((unsigned)h) << 16);
}

// rne-hi / trunc-lo split of one fp32 -> (rounded-u32, lo-float-bits)
static __device__ __forceinline__ void split1(float x, unsigned& uh, unsigned& ul) {
    unsigned u = __float_as_uint(x);
    uh = u + 0x7FFFu + ((u >> 16) & 1u);               // rne in upper 16
    ul = __float_as_uint(x - __uint_as_float(uh & 0xFFFF0000u));  // exact tail
}

// map global level-group index g (0..61) -> (raw pointer, local g)
static __device__ __forceinline__ const float* map_g(int g, const float* a0, const float* a1,
                                                     const float* a2, const float* a3,
                                                     const float* a4, int& lg) {
    if (g < 32) { lg = g;      return a0; }
    if (g < 48) { lg = g - 32; return a1; }
    if (g < 56) { lg = g - 48; return a2; }
    if (g < 60) { lg = g - 56; return a3; }
    lg = g - 60; return a4;
}

// ---------------- fused prep: X-transpose + weight pack + HT transpose ---
// blocks 0..15: X transpose; 16..79: weight pack; 80..1071: HT transpose.
__global__ __launch_bounds__(256) void k_prep3(
    const float* __restrict__ X, const float* __restrict__ wf,
    const float* __restrict__ wm, const float* __restrict__ wl,
    const float* __restrict__ b1, const float* __restrict__ bm,
    const float* __restrict__ bl, const float* __restrict__ af,
    const float* __restrict__ am,
    const float* __restrict__ a0, const float* __restrict__ a1,
    const float* __restrict__ a2, const float* __restrict__ a3,
    const float* __restrict__ a4,
    float* __restrict__ Wpack, float* __restrict__ Xt,
    unsigned short* __restrict__ Anth, unsigned short* __restrict__ Antl) {
    __shared__ float tile[64][65];
    const int t = threadIdx.x;
    const int b = blockIdx.x;
    if (b < 16) {
        // transpose X: (N,D) -> Xt (D,N)
        const int n0 = b * 64;
#pragma unroll
        for (int i = 0; i < 4; i++) {
            const int f   = i * 256 + t;
            const int row = f >> 4;
            const int c4  = f & 15;
            float4 v = *(const float4*)(X + (size_t)(n0 + row) * 64 + c4 * 4);
            tile[row][c4 * 4 + 0] = v.x;
            tile[row][c4 * 4 + 1] = v.y;
            tile[row][c4 * 4 + 2] = v.z;
            tile[row][c4 * 4 + 3] = v.w;
        }
        __syncthreads();
#pragma unroll
        for (int i = 0; i < 4; i++) {
            const int f    = i * 256 + t;
            const int drow = f >> 4;
            const int c4   = f & 15;
            float4 v;
            v.x = tile[c4 * 4 + 0][drow];
            v.y = tile[c4 * 4 + 1][drow];
            v.z = tile[c4 * 4 + 2][drow];
            v.w = tile[c4 * 4 + 3][drow];
            *(float4*)(Xt + (size_t)drow * 1024 + n0 + c4 * 4) = v;
        }
        return;
    }
    if (b < 80) {
        // weight pack: record[dm] of 48 floats
        const int id = (b - 16) * 256 + t;  // 0..16383
        float r[48];
#pragma unroll
        for (int q = 0; q < 48; q++) r[q] = 0.f;
#pragma unroll
        for (int q = 0; q < 3; q++) {
            r[0 + q] = sp10f(wf[id * 3 + q]);
            r[3 + q] = b1[id * 3 + q];
            r[6 + q] = tanhf(af[id * 3 + q]);
            r[39 + q] = sp10f(wl[id * 3 + q]);
        }
#pragma unroll
        for (int l = 0; l < 2; l++) {
            const size_t b9 = ((size_t)l * 16384 + id) * 9;
            const size_t b3 = ((size_t)l * 16384 + id) * 3;
#pragma unroll
            for (int q = 0; q < 9; q++) r[9 + l * 15 + q] = sp10f(wm[b9 + q]);
#pragma unroll
            for (int q = 0; q < 3; q++) {
                r[18 + l * 15 + q] = bm[b3 + q];
                r[21 + l * 15 + q] = tanhf(am[b3 + q]);
            }
        }
        r[42] = bl[id];
        float4* o = (float4*)(Wpack + (size_t)id * 48);
#pragma unroll
        for (int q = 0; q < 12; q++) o[q] = ((float4*)r)[q];
        return;
    }
    // HT transpose + sp10 + bf16 hi/lo split: An_t[g][k][m]
    const int idx = b - 80;          // 0..991
    const int g   = idx >> 4;        // 0..61
    const int rr  = idx & 15;
    const int m0  = (rr & 3) * 64;
    const int k0  = (rr >> 2) * 64;
    int lg;
    const float* A  = map_g(g, a0, a1, a2, a3, a4, lg);
    const float* Ag = A + (size_t)lg * 65536;

#pragma unroll
    for (int i = 0; i < 4; i++) {
        const int f   = i * 256 + t;
        const int row = f >> 4;
        const int c4  = f & 15;
        float4 v = *(const float4*)(Ag + (size_t)(m0 + row) * 256 + k0 + c4 * 4);
        tile[row][c4 * 4 + 0] = v.x;
        tile[row][c4 * 4 + 1] = v.y;
        tile[row][c4 * 4 + 2] = v.z;
        tile[row][c4 * 4 + 3] = v.w;
    }
    __syncthreads();

#pragma unroll
    for (int i = 0; i < 4; i++) {
        const int f    = i * 256 + t;
        const int krow = f >> 4;
        const int c4   = f & 15;
        float v0 = sp10f(tile[c4 * 4 + 0][krow]);
        float v1 = sp10f(tile[c4 * 4 + 1][krow]);
        float v2 = sp10f(tile[c4 * 4 + 2][krow]);
        float v3 = sp10f(tile[c4 * 4 + 3][krow]);
        unsigned short h0 = f2bf(v0), h1 = f2bf(v1), h2 = f2bf(v2), h3 = f2bf(v3);
        ushort4 hi, lo;
        hi.x = h0; hi.y = h1; hi.z = h2; hi.w = h3;
        lo.x = f2bf(v0 - bf2f(h0));
        lo.y = f2bf(v1 - bf2f(h1));
        lo.z = f2bf(v2 - bf2f(h2));
        lo.w = f2bf(v3 - bf2f(h3));
        const size_t dst = (size_t)g * 65536 + (size_t)(k0 + krow) * 256 + m0 + c4 * 4;
        *(ushort4*)(Anth + dst) = hi;
        *(ushort4*)(Antl + dst) = lo;
    }
}

// column sums (over m) from transposed hi/lo rows.
__global__ void k_csum_t(const unsigned short* __restrict__ Anth,
                         const unsigned short* __restrict__ Antl,
                         float* __restrict__ csum) {
    const int g    = blockIdx.x;
    const int w    = threadIdx.x >> 6;
    const int lane = threadIdx.x & 63;
    const int k    = blockIdx.y * 4 + w;
    const size_t base = (size_t)g * 65536 + k * 256 + lane * 4;
    uint2 vh = *(const uint2*)(Anth + base);
    uint2 vl = *(const uint2*)(Antl + base);
    float s = 0.f;
    s += bf2f((unsigned short)(vh.x & 0xFFFFu)) + bf2f((unsigned short)(vh.x >> 16));
    s += bf2f((unsigned short)(vh.y & 0xFFFFu)) + bf2f((unsigned short)(vh.y >> 16));
    s += bf2f((unsigned short)(vl.x & 0xFFFFu)) + bf2f((unsigned short)(vl.x >> 16));
    s += bf2f((unsigned short)(vl.y & 0xFFFFu)) + bf2f((unsigned short)(vl.y >> 16));
    for (int off = 32; off > 0; off >>= 1) s += __shfl_down(s, off);
    if (lane == 0) csum[g * 256 + k] = s;
}

// ---------------- phase 1: wave = one (d,m) chain, 2 n per lane (packed) -
// (round-14 configuration: m-split, 16.9 KB LDS, unroll 2)
__global__ __launch_bounds__(512, 1) void k_phase1(
    const float* __restrict__ Xt, const float* __restrict__ Wpack,
    unsigned short* __restrict__ P0h, unsigned short* __restrict__ P0l) {
    __shared__ float sT[128][33];
    __shared__ float sXd[2][128];
    const int j  = blockIdx.x;        // d-pair
    const int mc = blockIdx.y;        // m-chunk of 32
    const int n0 = blockIdx.z * 128;  // n base
    const int t  = threadIdx.x;
    const int w    = __builtin_amdgcn_readfirstlane(t >> 6);
    const int lane = t & 63;

    if (t < 256)
        sXd[t >> 7][t & 127] = Xt[(size_t)(2 * j + (t >> 7)) * 1024 + n0 + (t & 127)];
    __syncthreads();

    f32x2 xe0, xe1;
    xe0.x = sXd[0][lane]; xe0.y = sXd[0][64 + lane];
    xe1.x = sXd[1][lane]; xe1.y = sXd[1][64 + lane];

    const f32x2 one2 = sp2(1.f);
    f32x2 p0;

#pragma unroll 2
    for (int it = 0; it < 8; it++) {
        const int i  = it >> 1;
        const int e  = it & 1;
        const int mm = w * 4 + i;          // 0..31 within this m-chunk
        const int m  = mc * 32 + mm;       // global m
        const float* __restrict__ rp =
            Wpack + (size_t)(((2 * j + e) << 8) + m) * 48;
        float W1a[3], B1a[3], T1a[3], Wm[2][9], Bm[2][3], Tm[2][3], Wla[3];
#pragma unroll
        for (int r = 0; r < 3; r++) {
            W1a[r] = rp[r];
            B1a[r] = rp[3 + r];
            T1a[r] = rp[6 + r];
            Bm[0][r] = rp[18 + r];
            Tm[0][r] = rp[21 + r];
            Bm[1][r] = rp[33 + r];
            Tm[1][r] = rp[36 + r];
            Wla[r] = rp[39 + r];
        }
#pragma unroll
        for (int q = 0; q < 9; q++) {
            Wm[0][q] = rp[9 + q];
            Wm[1][q] = rp[24 + q];
        }
        const float Bla = rp[42];

        const f32x2 x = e ? xe1 : xe0;
        f32x2 phi[3], pd[3];
#pragma unroll
        for (int r = 0; r < 3; r++) {
            f32x2 z  = pkfma(x, sp2(W1a[r]), sp2(B1a[r]));
            f32x2 tz = ftanh2(z);
            f32x2 ta = sp2(T1a[r]);
            pd[r]  = sp2(W1a[r]) * pkfma(ta, pkfma(-tz, tz, one2), one2);
            phi[r] = pkfma(tz, ta, z);
        }
#pragma unroll
        for (int l = 0; l < 2; l++) {
            f32x2 nphi[3], npd[3];
#pragma unroll
            for (int q = 0; q < 3; q++) {
                f32x2 z  = sp2(Bm[l][q]);
                f32x2 dp = sp2(0.f);
#pragma unroll
                for (int r = 0; r < 3; r++) {
                    f32x2 wv = sp2(Wm[l][r * 3 + q]);
                    z  = pkfma(phi[r], wv, z);
                    dp = pkfma(pd[r],  wv, dp);
                }
                f32x2 tz = ftanh2(z);
                f32x2 ta = sp2(Tm[l][q]);
                nphi[q] = pkfma(tz, ta, z);
                npd[q]  = dp * pkfma(ta, pkfma(-tz, tz, one2), one2);
            }
#pragma unroll
            for (int q = 0; q < 3; q++) { phi[q] = nphi[q]; pd[q] = npd[q]; }
        }
        f32x2 z  = sp2(Bla);
        f32x2 dp = sp2(0.f);
#pragma unroll
        for (int r = 0; r < 3; r++) {
            f32x2 wv = sp2(Wla[r]);
            z  = pkfma(phi[r], wv, z);
            dp = pkfma(pd[r],  wv, dp);
        }
        // sigmoid via single exp2 per component
        f32x2 zs = z * sp2(-1.4426950408889634f);
        f32x2 s;
        s.x = __builtin_amdgcn_rcpf(1.f + __builtin_amdgcn_exp2f(zs.x));
        s.y = __builtin_amdgcn_rcpf(1.f + __builtin_amdgcn_exp2f(zs.y));
        f32x2 prod = dp * s * (one2 - s);
        if (e == 0) {
            p0 = prod;
        } else {
            sT[lane][mm]      = p0.x * prod.x;
            sT[64 + lane][mm] = p0.y * prod.y;
        }
    }
    __syncthreads();

    // cooperative coalesced write: sT (128 n x 32 m) -> P0h/P0l[j][n][m]
    const size_t base = ((size_t)j * N_PTS + n0) * M_DIM + mc * 32;
#pragma unroll
    for (int it = 0; it < 2; it++) {
        const int idx = it * 512 + t;   // 1024 float4 slots
        const int row = idx >> 3;       // n local 0..127
        const int c4  = idx & 7;        // m float4 (8 per row)
        float4 v;
        v.x = sT[row][c4 * 4 + 0];
        v.y = sT[row][c4 * 4 + 1];
        v.z = sT[row][c4 * 4 + 2];
        v.w = sT[row][c4 * 4 + 3];
        unsigned uh0, ul0, uh1, ul1, uh2, ul2, uh3, ul3;
        split1(v.x, uh0, ul0);
        split1(v.y, uh1, ul1);
        split1(v.z, uh2, ul2);
        split1(v.w, uh3, ul3);
        uint2 hp, lp;
        hp.x = __builtin_amdgcn_perm(uh1, uh0, 0x07060302u);
        hp.y = __builtin_amdgcn_perm(uh3, uh2, 0x07060302u);
        lp.x = __builtin_amdgcn_perm(ul1, ul0, 0x07060302u);
        lp.y = __builtin_amdgcn_perm(ul3, ul2, 0x07060302u);
        *(uint2*)(P0h + base + (size_t)row * M_DIM + c4 * 4) = hp;
        *(uint2*)(P0l + base + (size_t)row * M_DIM + c4 * 4) = lp;
    }
}

// ---------------- pair-product + bf16 split (between HT levels) ----------
// Qh/Ql[q] = split(G[2q] * G[2q+1]) elementwise. grid = npairs*128 blocks.
__global__ __launch_bounds__(256) void k_pair(const float* __restrict__ G,
                                              unsigned short* __restrict__ Qh,
                                              unsigned short* __restrict__ Ql) {
    const int i = blockIdx.x * 256 + threadIdx.x;
#pragma unroll
    for (int s = 0; s < 2; s++) {
        const int idx = i * 2 + s;        // float4 slot in output space
        const int q = idx >> 16;          // pair index (65536 float4/group)
        const int r = idx & 65535;
        const float4 a = *(const float4*)(G + ((size_t)(2 * q) << 18) + r * 4);
        const float4 b = *(const float4*)(G + ((size_t)(2 * q + 1) << 18) + r * 4);
        float4 v;
        v.x = a.x * b.x; v.y = a.y * b.y; v.z = a.z * b.z; v.w = a.w * b.w;
        unsigned uh0, ul0, uh1, ul1, uh2, ul2, uh3, ul3;
        split1(v.x, uh0, ul0);
        split1(v.y, uh1, ul1);
        split1(v.z, uh2, ul2);
        split1(v.w, uh3, ul3);
        uint2 hp, lp;
        hp.x = __builtin_amdgcn_perm(uh1, uh0, 0x07060302u);
        hp.y = __builtin_amdgcn_perm(uh3, uh2, 0x07060302u);
        lp.x = __builtin_amdgcn_perm(ul1, ul0, 0x07060302u);
        lp.y = __builtin_amdgcn_perm(ul3, ul2, 0x07060302u);
        *(uint2*)(Qh + ((size_t)q << 18) + r * 4) = hp;
        *(uint2*)(Ql + ((size_t)q << 18) + r * 4) = lp;
    }
}

#define LDST64 72  // LDS row stride in bf16 elems (64 + 8 pad = 144 B)

// ---------------- all HT levels: 64x64 GEMM, BK=64, presplit pure copy ---
__global__ __launch_bounds__(256, 4) void k_g64ps(
    const unsigned short* __restrict__ Th, const unsigned short* __restrict__ Tl,
    const unsigned short* __restrict__ Bh, const unsigned short* __restrict__ Bl,
    const float* __restrict__ csum, float* __restrict__ Tout) {
    __shared__ unsigned short sAh[64 * LDST64];
    __shared__ unsigned short sAl[64 * LDST64];
    __shared__ unsigned short sBh[64 * LDST64];
    __shared__ unsigned short sBl[64 * LDST64];

    const int g  = blockIdx.z;
    const int n0 = blockIdx.x * 64;
    const int k0 = blockIdx.y * 64;
    const unsigned short* Thg = Th + ((size_t)g << 18);
    const unsigned short* Tlg = Tl + ((size_t)g << 18);
    const unsigned short* Bhg = Bh + ((size_t)g << 16);
    const unsigned short* Blg = Bl + ((size_t)g << 16);

    const int tid  = threadIdx.x;
    const int lane = tid & 63;
    const int w    = tid >> 6;
    const int wr   = w >> 1;
    const int wc   = w & 1;
    const int lr   = lane & 15;
    const int lk   = lane >> 4;

    f32x4 acc[2][2];
#pragma unroll
    for (int a = 0; a < 2; a++)
#pragma unroll
        for (int b = 0; b < 2; b++) acc[a][b] = (f32x4){0.f, 0.f, 0.f, 0.f};

    for (int kb = 0; kb < 256; kb += 64) {
#pragma unroll
        for (int i = 0; i < 2; i++) {
            const int idx = i * 256 + tid;   // 512 uint4 slots per buffer
            const int row = idx >> 3;        // 0..63
            const int seg = idx & 7;         // 8 ushorts each
            const size_t srcA = (size_t)(n0 + row) * 256 + kb + seg * 8;
            const size_t srcB = (size_t)(k0 + row) * 256 + kb + seg * 8;
            *(uint4*)&sAh[row * LDST64 + seg * 8] = *(const uint4*)(Thg + srcA);
            *(uint4*)&sAl[row * LDST64 + seg * 8] = *(const uint4*)(Tlg + srcA);
            *(uint4*)&sBh[row * LDST64 + seg * 8] = *(const uint4*)(Bhg + srcB);
            *(uint4*)&sBl[row * LDST64 + seg * 8] = *(const uint4*)(Blg + srcB);
        }
        __syncthreads();

        s16x8 ah[2][2], al[2][2], bh[2][2], bl[2][2];
#pragma unroll
        for (int nt = 0; nt < 2; nt++)
#pragma unroll
            for (int ks = 0; ks < 2; ks++) {
                const int off = (wr * 32 + nt * 16 + lr) * LDST64 + ks * 32 + lk * 8;
                ah[nt][ks] = *(const s16x8*)&sAh[off];
                al[nt][ks] = *(const s16x8*)&sAl[off];
            }
#pragma unroll
        for (int kt = 0; kt < 2; kt++)
#pragma unroll
            for (int ks = 0; ks < 2; ks++) {
                const int off = (wc * 32 + kt * 16 + lr) * LDST64 + ks * 32 + lk * 8;
                bh[kt][ks] = *(const s16x8*)&sBh[off];
                bl[kt][ks] = *(const s16x8*)&sBl[off];
            }
#pragma unroll
        for (int ks = 0; ks < 2; ks++)
#pragma unroll
            for (int nt = 0; nt < 2; nt++)
#pragma unroll
                for (int kt = 0; kt < 2; kt++) {
                    acc[nt][kt] = __builtin_amdgcn_mfma_f32_16x16x32_bf16(ah[nt][ks], bh[kt][ks], acc[nt][kt], 0, 0, 0);
                    acc[nt][kt] = __builtin_amdgcn_mfma_f32_16x16x32_bf16(ah[nt][ks], bl[kt][ks], acc[nt][kt], 0, 0, 0);
                    acc[nt][kt] = __builtin_amdgcn_mfma_f32_16x16x32_bf16(al[nt][ks], bh[kt][ks], acc[nt][kt], 0, 0, 0);
                }
        __syncthreads();
    }

    float* Og = Tout + ((size_t)g << 18);
#pragma unroll
    for (int kt = 0; kt < 2; kt++) {
        const int col = k0 + wc * 32 + kt * 16 + lr;
        const float inv = 1.0f / csum[g * 256 + col];
#pragma unroll
        for (int nt = 0; nt < 2; nt++) {
            const int rbase = n0 + wr * 32 + nt * 16 + lk * 4;
#pragma unroll
            for (int r = 0; r < 4; r++)
                Og[(size_t)(rbase + r) * 256 + col] = acc[nt][kt][r] * inv;
        }
    }
}

// ---------------- level 5: pair-product + normalized dot -----------------
__global__ void k_l5(const float* __restrict__ Tin, const float* __restrict__ a5,
                     float* __restrict__ out) {
    const int n = blockIdx.x;
    const int m = threadIdx.x;
    __shared__ float sv[256], sw[256];
    float w = sp10f(a5[m]);
    float v = Tin[(size_t)n * 256 + m] * Tin[(size_t)(N_PTS + n) * 256 + m] * w;
    sv[m] = v;
    sw[m] = w;
    __syncthreads();
    for (int s = 128; s > 0; s >>= 1) {
        if (m < s) { sv[m] += sv[m + s]; sw[m] += sw[m + s]; }
        __syncthreads();
    }
    if (m == 0) out[n] = sv[0] / sw[0];
}

extern "C" void kernel_launch(void* const* d_in, const int* in_sizes, int n_in,
                              void* d_out, int out_size, void* d_ws, size_t ws_size,
                              hipStream_t stream) {
    const float* X  = (const float*)d_in[0];
    const float* wf = (const float*)d_in[1];
    const float* wm = (const float*)d_in[2];
    const float* wl = (const float*)d_in[3];
    const float* b1 = (const float*)d_in[4];
    const float* bm = (const float*)d_in[5];
    const float* bl = (const float*)d_in[6];
    const float* af = (const float*)d_in[7];
    const float* am = (const float*)d_in[8];
    const float* a0 = (const float*)d_in[9];
    const float* a1 = (const float*)d_in[10];
    const float* a2 = (const float*)d_in[11];
    const float* a3 = (const float*)d_in[12];
    const float* a4 = (const float*)d_in[13];
    const float* a5 = (const float*)d_in[14];
    float* out = (float*)d_out;

    float* ws    = (float*)d_ws;
    float* Wpack = ws;                                 // 786432 f
    float* Xt    = Wpack + 786432;                     // 65536 f
    float* csum  = Xt + 65536;                         // 15872 f
    unsigned short* Anth = (unsigned short*)(csum + 15872);  // 62*65536 us
    unsigned short* Antl = Anth + (size_t)62 * 65536;        // 62*65536 us
    unsigned short* P0h  = Antl + (size_t)62 * 65536;        // 32*262144 us
    unsigned short* P0l  = P0h + (size_t)32 * 262144;        // 32*262144 us
    float* Gbuf  = (float*)(P0l + (size_t)32 * 262144);      // 32*262144 f
    unsigned short* Qh   = (unsigned short*)(Gbuf + (size_t)32 * 262144); // 16*262144 us
    unsigned short* Ql   = Qh + (size_t)16 * 262144;         // 16*262144 us

    k_prep3<<<1072, 256, 0, stream>>>(X, wf, wm, wl, b1, bm, bl, af, am,
                                      a0, a1, a2, a3, a4, Wpack, Xt, Anth, Antl);
    k_csum_t<<<dim3(62, 64), 256, 0, stream>>>(Anth, Antl, csum);
    k_phase1<<<dim3(32, 8, 8), 512, 0, stream>>>(Xt, Wpack, P0h, P0l);

    // L0: 32 groups (presplit P0) -> Gbuf fp32
    k_g64ps<<<dim3(16, 4, 32), 256, 0, stream>>>(P0h, P0l, Anth, Antl, csum, Gbuf);
    // L1: pair 32->16 (presplit), GEMM
    k_pair<<<2048, 256, 0, stream>>>(Gbuf, Qh, Ql);
    k_g64ps<<<dim3(16, 4, 16), 256, 0, stream>>>(Qh, Ql, Anth + (size_t)32 * 65536,
                                                 Antl + (size_t)32 * 65536,
                                                 csum + 32 * 256, Gbuf);
    // L2: pair 16->8, GEMM
    k_pair<<<1024, 256, 0, stream>>>(Gbuf, Qh, Ql);
    k_g64ps<<<dim3(16, 4, 8), 256, 0, stream>>>(Qh, Ql, Anth + (size_t)48 * 65536,
                                                Antl + (size_t)48 * 65536,
                                                csum + 48 * 256, Gbuf);
    // L3: pair 8->4, GEMM
    k_pair<<<512, 256, 0, stream>>>(Gbuf, Qh, Ql);
    k_g64ps<<<dim3(16, 4, 4), 256, 0, stream>>>(Qh, Ql, Anth + (size_t)56 * 65536,
                                                Antl + (size_t)56 * 65536,
                                                csum + 56 * 256, Gbuf);
    // L4: pair 4->2, GEMM
    k_pair<<<256, 256, 0, stream>>>(Gbuf, Qh, Ql);
    k_g64ps<<<dim3(16, 4, 2), 256, 0, stream>>>(Qh, Ql, Anth + (size_t)60 * 65536,
                                                Antl + (size_t)60 * 65536,
                                                csum + 60 * 256, Gbuf);
    // level 5
    k_l5<<<N_PTS, 256, 0, stream>>>(Gbuf, a5, out);
}

// Round 19
// 145.506 us; speedup vs baseline: 1.6057x; 1.1169x over previous
//
#include <hip/hip_runtime.h>
#include <cstdint>
#include <cstddef>

// Problem constants
#define D_DIM 64
#define M_DIM 256
#define N_PTS 1024

typedef __attribute__((ext_vector_type(4))) float f32x4;
typedef __attribute__((ext_vector_type(2))) float f32x2;
typedef __attribute__((ext_vector_type(8))) short s16x8;

static __device__ __forceinline__ f32x2 pkfma(f32x2 a, f32x2 b, f32x2 c) {
#if __has_builtin(__builtin_elementwise_fma)
    return __builtin_elementwise_fma(a, b, c);
#else
    f32x2 r; r.x = fmaf(a.x, b.x, c.x); r.y = fmaf(a.y, b.y, c.y); return r;
#endif
}
static __device__ __forceinline__ f32x2 sp2(float s) {
    f32x2 r; r.x = s; r.y = s; return r;
}

static __device__ __forceinline__ float sp10f(float x) {
    // softplus(10x)/10, numerically stable, matches jax.nn.softplus
    float t = 10.f * x;
    return 0.1f * (fmaxf(t, 0.f) + log1pf(__expf(-fabsf(t))));
}

// packed branch-free tanh: 1 - 2/(exp2(x*2log2e)+1); single v_exp per lane
static __device__ __forceinline__ f32x2 ftanh2(f32x2 x) {
    f32x2 xs = x * sp2(2.88539008177793f);   // 2*log2(e)
    f32x2 e;
    e.x = __builtin_amdgcn_exp2f(xs.x);
    e.y = __builtin_amdgcn_exp2f(xs.y);
    f32x2 ep = e + sp2(1.f);
    f32x2 r;
    r.x = __builtin_amdgcn_rcpf(ep.x);
    r.y = __builtin_amdgcn_rcpf(ep.y);
    return pkfma(sp2(-2.f), r, sp2(1.f));
}

static __device__ __forceinline__ unsigned short f2bf(float x) {
    unsigned u = __float_as_uint(x);
    u = u + 0x7FFFu + ((u >> 16) & 1u);   // round-to-nearest-even
    return (unsigned short)(u >> 16);
}
static __device__ __forceinline__ float bf2f(unsigned short h) {
    return __uint_as_float(((unsigned)h) << 16);
}

// rne-hi / trunc-lo split of one fp32 -> (rounded-u32, lo-float-bits)
static __device__ __forceinline__ void split1(float x, unsigned& uh, unsigned& ul) {
    unsigned u = __float_as_uint(x);
    uh = u + 0x7FFFu + ((u >> 16) & 1u);               // rne in upper 16
    ul = __float_as_uint(x - __uint_as_float(uh & 0xFFFF0000u));  // exact tail
}

// map global level-group index g (0..61) -> (raw pointer, local g)
static __device__ __forceinline__ const float* map_g(int g, const float* a0, const float* a1,
                                                     const float* a2, const float* a3,
                                                     const float* a4, int& lg) {
    if (g < 32) { lg = g;      return a0; }
    if (g < 48) { lg = g - 32; return a1; }
    if (g < 56) { lg = g - 48; return a2; }
    if (g < 60) { lg = g - 56; return a3; }
    lg = g - 60; return a4;
}

// ---------------- fused prep: X-transpose + weight pack + HT transpose ---
// blocks 0..15: X transpose; 16..79: weight pack; 80..1071: HT transpose.
__global__ __launch_bounds__(256) void k_prep3(
    const float* __restrict__ X, const float* __restrict__ wf,
    const float* __restrict__ wm, const float* __restrict__ wl,
    const float* __restrict__ b1, const float* __restrict__ bm,
    const float* __restrict__ bl, const float* __restrict__ af,
    const float* __restrict__ am,
    const float* __restrict__ a0, const float* __restrict__ a1,
    const float* __restrict__ a2, const float* __restrict__ a3,
    const float* __restrict__ a4,
    float* __restrict__ Wpack, float* __restrict__ Xt,
    unsigned short* __restrict__ Anth, unsigned short* __restrict__ Antl) {
    __shared__ float tile[64][65];
    const int t = threadIdx.x;
    const int b = blockIdx.x;
    if (b < 16) {
        // transpose X: (N,D) -> Xt (D,N)
        const int n0 = b * 64;
#pragma unroll
        for (int i = 0; i < 4; i++) {
            const int f   = i * 256 + t;
            const int row = f >> 4;
            const int c4  = f & 15;
            float4 v = *(const float4*)(X + (size_t)(n0 + row) * 64 + c4 * 4);
            tile[row][c4 * 4 + 0] = v.x;
            tile[row][c4 * 4 + 1] = v.y;
            tile[row][c4 * 4 + 2] = v.z;
            tile[row][c4 * 4 + 3] = v.w;
        }
        __syncthreads();
#pragma unroll
        for (int i = 0; i < 4; i++) {
            const int f    = i * 256 + t;
            const int drow = f >> 4;
            const int c4   = f & 15;
            float4 v;
            v.x = tile[c4 * 4 + 0][drow];
            v.y = tile[c4 * 4 + 1][drow];
            v.z = tile[c4 * 4 + 2][drow];
            v.w = tile[c4 * 4 + 3][drow];
            *(float4*)(Xt + (size_t)drow * 1024 + n0 + c4 * 4) = v;
        }
        return;
    }
    if (b < 80) {
        // weight pack: record[dm] of 48 floats
        const int id = (b - 16) * 256 + t;  // 0..16383
        float r[48];
#pragma unroll
        for (int q = 0; q < 48; q++) r[q] = 0.f;
#pragma unroll
        for (int q = 0; q < 3; q++) {
            r[0 + q] = sp10f(wf[id * 3 + q]);
            r[3 + q] = b1[id * 3 + q];
            r[6 + q] = tanhf(af[id * 3 + q]);
            r[39 + q] = sp10f(wl[id * 3 + q]);
        }
#pragma unroll
        for (int l = 0; l < 2; l++) {
            const size_t b9 = ((size_t)l * 16384 + id) * 9;
            const size_t b3 = ((size_t)l * 16384 + id) * 3;
#pragma unroll
            for (int q = 0; q < 9; q++) r[9 + l * 15 + q] = sp10f(wm[b9 + q]);
#pragma unroll
            for (int q = 0; q < 3; q++) {
                r[18 + l * 15 + q] = bm[b3 + q];
                r[21 + l * 15 + q] = tanhf(am[b3 + q]);
            }
        }
        r[42] = bl[id];
        float4* o = (float4*)(Wpack + (size_t)id * 48);
#pragma unroll
        for (int q = 0; q < 12; q++) o[q] = ((float4*)r)[q];
        return;
    }
    // HT transpose + sp10 + bf16 hi/lo split: An_t[g][k][m]
    const int idx = b - 80;          // 0..991
    const int g   = idx >> 4;        // 0..61
    const int rr  = idx & 15;
    const int m0  = (rr & 3) * 64;
    const int k0  = (rr >> 2) * 64;
    int lg;
    const float* A  = map_g(g, a0, a1, a2, a3, a4, lg);
    const float* Ag = A + (size_t)lg * 65536;

#pragma unroll
    for (int i = 0; i < 4; i++) {
        const int f   = i * 256 + t;
        const int row = f >> 4;
        const int c4  = f & 15;
        float4 v = *(const float4*)(Ag + (size_t)(m0 + row) * 256 + k0 + c4 * 4);
        tile[row][c4 * 4 + 0] = v.x;
        tile[row][c4 * 4 + 1] = v.y;
        tile[row][c4 * 4 + 2] = v.z;
        tile[row][c4 * 4 + 3] = v.w;
    }
    __syncthreads();

#pragma unroll
    for (int i = 0; i < 4; i++) {
        const int f    = i * 256 + t;
        const int krow = f >> 4;
        const int c4   = f & 15;
        float v0 = sp10f(tile[c4 * 4 + 0][krow]);
        float v1 = sp10f(tile[c4 * 4 + 1][krow]);
        float v2 = sp10f(tile[c4 * 4 + 2][krow]);
        float v3 = sp10f(tile[c4 * 4 + 3][krow]);
        unsigned short h0 = f2bf(v0), h1 = f2bf(v1), h2 = f2bf(v2), h3 = f2bf(v3);
        ushort4 hi, lo;
        hi.x = h0; hi.y = h1; hi.z = h2; hi.w = h3;
        lo.x = f2bf(v0 - bf2f(h0));
        lo.y = f2bf(v1 - bf2f(h1));
        lo.z = f2bf(v2 - bf2f(h2));
        lo.w = f2bf(v3 - bf2f(h3));
        const size_t dst = (size_t)g * 65536 + (size_t)(k0 + krow) * 256 + m0 + c4 * 4;
        *(ushort4*)(Anth + dst) = hi;
        *(ushort4*)(Antl + dst) = lo;
    }
}

// column sums (over m) from transposed hi/lo rows.
__global__ void k_csum_t(const unsigned short* __restrict__ Anth,
                         const unsigned short* __restrict__ Antl,
                         float* __restrict__ csum) {
    const int g    = blockIdx.x;
    const int w    = threadIdx.x >> 6;
    const int lane = threadIdx.x & 63;
    const int k    = blockIdx.y * 4 + w;
    const size_t base = (size_t)g * 65536 + k * 256 + lane * 4;
    uint2 vh = *(const uint2*)(Anth + base);
    uint2 vl = *(const uint2*)(Antl + base);
    float s = 0.f;
    s += bf2f((unsigned short)(vh.x & 0xFFFFu)) + bf2f((unsigned short)(vh.x >> 16));
    s += bf2f((unsigned short)(vh.y & 0xFFFFu)) + bf2f((unsigned short)(vh.y >> 16));
    s += bf2f((unsigned short)(vl.x & 0xFFFFu)) + bf2f((unsigned short)(vl.x >> 16));
    s += bf2f((unsigned short)(vl.y & 0xFFFFu)) + bf2f((unsigned short)(vl.y >> 16));
    for (int off = 32; off > 0; off >>= 1) s += __shfl_down(s, off);
    if (lane == 0) csum[g * 256 + k] = s;
}

// ---------------- phase 1: wave = one (d,m) chain, 2 n per lane (packed) -
// (round-14 configuration: m-split, 16.9 KB LDS, unroll 2)
__global__ __launch_bounds__(512, 1) void k_phase1(
    const float* __restrict__ Xt, const float* __restrict__ Wpack,
    unsigned short* __restrict__ P0h, unsigned short* __restrict__ P0l) {
    __shared__ float sT[128][33];
    __shared__ float sXd[2][128];
    const int j  = blockIdx.x;        // d-pair
    const int mc = blockIdx.y;        // m-chunk of 32
    const int n0 = blockIdx.z * 128;  // n base
    const int t  = threadIdx.x;
    const int w    = __builtin_amdgcn_readfirstlane(t >> 6);
    const int lane = t & 63;

    if (t < 256)
        sXd[t >> 7][t & 127] = Xt[(size_t)(2 * j + (t >> 7)) * 1024 + n0 + (t & 127)];
    __syncthreads();

    f32x2 xe0, xe1;
    xe0.x = sXd[0][lane]; xe0.y = sXd[0][64 + lane];
    xe1.x = sXd[1][lane]; xe1.y = sXd[1][64 + lane];

    const f32x2 one2 = sp2(1.f);
    f32x2 p0;

#pragma unroll 2
    for (int it = 0; it < 8; it++) {
        const int i  = it >> 1;
        const int e  = it & 1;
        const int mm = w * 4 + i;          // 0..31 within this m-chunk
        const int m  = mc * 32 + mm;       // global m
        const float* __restrict__ rp =
            Wpack + (size_t)(((2 * j + e) << 8) + m) * 48;
        float W1a[3], B1a[3], T1a[3], Wm[2][9], Bm[2][3], Tm[2][3], Wla[3];
#pragma unroll
        for (int r = 0; r < 3; r++) {
            W1a[r] = rp[r];
            B1a[r] = rp[3 + r];
            T1a[r] = rp[6 + r];
            Bm[0][r] = rp[18 + r];
            Tm[0][r] = rp[21 + r];
            Bm[1][r] = rp[33 + r];
            Tm[1][r] = rp[36 + r];
            Wla[r] = rp[39 + r];
        }
#pragma unroll
        for (int q = 0; q < 9; q++) {
            Wm[0][q] = rp[9 + q];
            Wm[1][q] = rp[24 + q];
        }
        const float Bla = rp[42];

        const f32x2 x = e ? xe1 : xe0;
        f32x2 phi[3], pd[3];
#pragma unroll
        for (int r = 0; r < 3; r++) {
            f32x2 z  = pkfma(x, sp2(W1a[r]), sp2(B1a[r]));
            f32x2 tz = ftanh2(z);
            f32x2 ta = sp2(T1a[r]);
            pd[r]  = sp2(W1a[r]) * pkfma(ta, pkfma(-tz, tz, one2), one2);
            phi[r] = pkfma(tz, ta, z);
        }
#pragma unroll
        for (int l = 0; l < 2; l++) {
            f32x2 nphi[3], npd[3];
#pragma unroll
            for (int q = 0; q < 3; q++) {
                f32x2 z  = sp2(Bm[l][q]);
                f32x2 dp = sp2(0.f);
#pragma unroll
                for (int r = 0; r < 3; r++) {
                    f32x2 wv = sp2(Wm[l][r * 3 + q]);
                    z  = pkfma(phi[r], wv, z);
                    dp = pkfma(pd[r],  wv, dp);
                }
                f32x2 tz = ftanh2(z);
                f32x2 ta = sp2(Tm[l][q]);
                nphi[q] = pkfma(tz, ta, z);
                npd[q]  = dp * pkfma(ta, pkfma(-tz, tz, one2), one2);
            }
#pragma unroll
            for (int q = 0; q < 3; q++) { phi[q] = nphi[q]; pd[q] = npd[q]; }
        }
        f32x2 z  = sp2(Bla);
        f32x2 dp = sp2(0.f);
#pragma unroll
        for (int r = 0; r < 3; r++) {
            f32x2 wv = sp2(Wla[r]);
            z  = pkfma(phi[r], wv, z);
            dp = pkfma(pd[r],  wv, dp);
        }
        // sigmoid via single exp2 per component
        f32x2 zs = z * sp2(-1.4426950408889634f);
        f32x2 s;
        s.x = __builtin_amdgcn_rcpf(1.f + __builtin_amdgcn_exp2f(zs.x));
        s.y = __builtin_amdgcn_rcpf(1.f + __builtin_amdgcn_exp2f(zs.y));
        f32x2 prod = dp * s * (one2 - s);
        if (e == 0) {
            p0 = prod;
        } else {
            sT[lane][mm]      = p0.x * prod.x;
            sT[64 + lane][mm] = p0.y * prod.y;
        }
    }
    __syncthreads();

    // cooperative coalesced write: sT (128 n x 32 m) -> P0h/P0l[j][n][m]
    const size_t base = ((size_t)j * N_PTS + n0) * M_DIM + mc * 32;
#pragma unroll
    for (int it = 0; it < 2; it++) {
        const int idx = it * 512 + t;   // 1024 float4 slots
        const int row = idx >> 3;       // n local 0..127
        const int c4  = idx & 7;        // m float4 (8 per row)
        float4 v;
        v.x = sT[row][c4 * 4 + 0];
        v.y = sT[row][c4 * 4 + 1];
        v.z = sT[row][c4 * 4 + 2];
        v.w = sT[row][c4 * 4 + 3];
        unsigned uh0, ul0, uh1, ul1, uh2, ul2, uh3, ul3;
        split1(v.x, uh0, ul0);
        split1(v.y, uh1, ul1);
        split1(v.z, uh2, ul2);
        split1(v.w, uh3, ul3);
        uint2 hp, lp;
        hp.x = __builtin_amdgcn_perm(uh1, uh0, 0x07060302u);
        hp.y = __builtin_amdgcn_perm(uh3, uh2, 0x07060302u);
        lp.x = __builtin_amdgcn_perm(ul1, ul0, 0x07060302u);
        lp.y = __builtin_amdgcn_perm(ul3, ul2, 0x07060302u);
        *(uint2*)(P0h + base + (size_t)row * M_DIM + c4 * 4) = hp;
        *(uint2*)(P0l + base + (size_t)row * M_DIM + c4 * 4) = lp;
    }
}

#define LDST64 72  // LDS row stride in bf16 elems (64 + 8 pad = 144 B)

// ---------------- L0: 64x64 GEMM, BK=64, PRE-SPLIT input (pure copy) -----
__global__ __launch_bounds__(256, 4) void k_g64ps(
    const unsigned short* __restrict__ Th, const unsigned short* __restrict__ Tl,
    const unsigned short* __restrict__ Bh, const unsigned short* __restrict__ Bl,
    const float* __restrict__ csum, float* __restrict__ Tout) {
    __shared__ unsigned short sAh[64 * LDST64];
    __shared__ unsigned short sAl[64 * LDST64];
    __shared__ unsigned short sBh[64 * LDST64];
    __shared__ unsigned short sBl[64 * LDST64];

    const int g  = blockIdx.z;
    const int n0 = blockIdx.x * 64;
    const int k0 = blockIdx.y * 64;
    const unsigned short* Thg = Th + ((size_t)g << 18);
    const unsigned short* Tlg = Tl + ((size_t)g << 18);
    const unsigned short* Bhg = Bh + ((size_t)g << 16);
    const unsigned short* Blg = Bl + ((size_t)g << 16);

    const int tid  = threadIdx.x;
    const int lane = tid & 63;
    const int w    = tid >> 6;
    const int wr   = w >> 1;
    const int wc   = w & 1;
    const int lr   = lane & 15;
    const int lk   = lane >> 4;

    f32x4 acc[2][2];
#pragma unroll
    for (int a = 0; a < 2; a++)
#pragma unroll
        for (int b = 0; b < 2; b++) acc[a][b] = (f32x4){0.f, 0.f, 0.f, 0.f};

    for (int kb = 0; kb < 256; kb += 64) {
#pragma unroll
        for (int i = 0; i < 2; i++) {
            const int idx = i * 256 + tid;   // 512 uint4 slots per buffer
            const int row = idx >> 3;        // 0..63
            const int seg = idx & 7;         // 8 ushorts each
            const size_t srcA = (size_t)(n0 + row) * 256 + kb + seg * 8;
            const size_t srcB = (size_t)(k0 + row) * 256 + kb + seg * 8;
            *(uint4*)&sAh[row * LDST64 + seg * 8] = *(const uint4*)(Thg + srcA);
            *(uint4*)&sAl[row * LDST64 + seg * 8] = *(const uint4*)(Tlg + srcA);
            *(uint4*)&sBh[row * LDST64 + seg * 8] = *(const uint4*)(Bhg + srcB);
            *(uint4*)&sBl[row * LDST64 + seg * 8] = *(const uint4*)(Blg + srcB);
        }
        __syncthreads();

        s16x8 ah[2][2], al[2][2], bh[2][2], bl[2][2];
#pragma unroll
        for (int nt = 0; nt < 2; nt++)
#pragma unroll
            for (int ks = 0; ks < 2; ks++) {
                const int off = (wr * 32 + nt * 16 + lr) * LDST64 + ks * 32 + lk * 8;
                ah[nt][ks] = *(const s16x8*)&sAh[off];
                al[nt][ks] = *(const s16x8*)&sAl[off];
            }
#pragma unroll
        for (int kt = 0; kt < 2; kt++)
#pragma unroll
            for (int ks = 0; ks < 2; ks++) {
                const int off = (wc * 32 + kt * 16 + lr) * LDST64 + ks * 32 + lk * 8;
                bh[kt][ks] = *(const s16x8*)&sBh[off];
                bl[kt][ks] = *(const s16x8*)&sBl[off];
            }
#pragma unroll
        for (int ks = 0; ks < 2; ks++)
#pragma unroll
            for (int nt = 0; nt < 2; nt++)
#pragma unroll
                for (int kt = 0; kt < 2; kt++) {
                    acc[nt][kt] = __builtin_amdgcn_mfma_f32_16x16x32_bf16(ah[nt][ks], bh[kt][ks], acc[nt][kt], 0, 0, 0);
                    acc[nt][kt] = __builtin_amdgcn_mfma_f32_16x16x32_bf16(ah[nt][ks], bl[kt][ks], acc[nt][kt], 0, 0, 0);
                    acc[nt][kt] = __builtin_amdgcn_mfma_f32_16x16x32_bf16(al[nt][ks], bh[kt][ks], acc[nt][kt], 0, 0, 0);
                }
        __syncthreads();
    }

    float* Og = Tout + ((size_t)g << 18);
#pragma unroll
    for (int kt = 0; kt < 2; kt++) {
        const int col = k0 + wc * 32 + kt * 16 + lr;
        const float inv = 1.0f / csum[g * 256 + col];
#pragma unroll
        for (int nt = 0; nt < 2; nt++) {
            const int rbase = n0 + wr * 32 + nt * 16 + lk * 4;
#pragma unroll
            for (int r = 0; r < 4; r++)
                Og[(size_t)(rbase + r) * 256 + col] = acc[nt][kt][r] * inv;
        }
    }
}

// ---------------- L1-L4: 64x64-tile, BK=64, paired GEMM ------------------
// stage-A split uses TRUNCATION (hi = raw high 16 bits, lo = v - hi, exact
// hi+lo == v) -> perm packs hi directly from raw bits; saves ~2/3 of the
// split VALU vs rne. Dropped Tl*Bl term grows 2^-25 -> 2^-24 rel: negligible.
__global__ __launch_bounds__(256, 4) void k_gemm64(const float* __restrict__ Tin,
                                                   const unsigned short* __restrict__ Bh,
                                                   const unsigned short* __restrict__ Bl,
                                                   const float* __restrict__ csum,
                                                   float* __restrict__ Tout) {
    __shared__ unsigned short sAh[64 * LDST64];
    __shared__ unsigned short sAl[64 * LDST64];
    __shared__ unsigned short sBh[64 * LDST64];
    __shared__ unsigned short sBl[64 * LDST64];

    const int g  = blockIdx.z;
    const int n0 = blockIdx.x * 64;
    const int k0 = blockIdx.y * 64;
    const float* T0  = Tin + (size_t)(2 * g) * N_PTS * 256;
    const float* T1p = T0 + (size_t)N_PTS * 256;
    const unsigned short* Bhg = Bh + ((size_t)g << 16);
    const unsigned short* Blg = Bl + ((size_t)g << 16);

    const int tid  = threadIdx.x;
    const int lane = tid & 63;
    const int w    = tid >> 6;
    const int wr   = w >> 1;
    const int wc   = w & 1;
    const int lr   = lane & 15;
    const int lk   = lane >> 4;

    f32x4 acc[2][2];
#pragma unroll
    for (int a = 0; a < 2; a++)
#pragma unroll
        for (int b = 0; b < 2; b++) acc[a][b] = (f32x4){0.f, 0.f, 0.f, 0.f};

    for (int kb = 0; kb < 256; kb += 64) {
        // stage A: 64 n x 64 m fp32 pair-product -> trunc split hi/lo
#pragma unroll
        for (int i = 0; i < 4; i++) {
            const int idx = i * 256 + tid;   // 1024 float4 slots
            const int row = idx >> 4;        // 0..63
            const int c4  = idx & 15;        // 16 float4 per row
            float4 v = *(const float4*)(T0 + (size_t)(n0 + row) * 256 + kb + c4 * 4);
            float4 u = *(const float4*)(T1p + (size_t)(n0 + row) * 256 + kb + c4 * 4);
            v.x *= u.x; v.y *= u.y; v.z *= u.z; v.w *= u.w;
            const unsigned b0 = __float_as_uint(v.x);
            const unsigned b1 = __float_as_uint(v.y);
            const unsigned b2 = __float_as_uint(v.z);
            const unsigned b3 = __float_as_uint(v.w);
            uint2 hp, lp;
            hp.x = __builtin_amdgcn_perm(b1, b0, 0x07060302u);
            hp.y = __builtin_amdgcn_perm(b3, b2, 0x07060302u);
            const float l0 = v.x - __uint_as_float(b0 & 0xFFFF0000u);
            const float l1 = v.y - __uint_as_float(b1 & 0xFFFF0000u);
            const float l2 = v.z - __uint_as_float(b2 & 0xFFFF0000u);
            const float l3 = v.w - __uint_as_float(b3 & 0xFFFF0000u);
            lp.x = __builtin_amdgcn_perm(__float_as_uint(l1), __float_as_uint(l0), 0x07060302u);
            lp.y = __builtin_amdgcn_perm(__float_as_uint(l3), __float_as_uint(l2), 0x07060302u);
            *(uint2*)&sAh[row * LDST64 + c4 * 4] = hp;
            *(uint2*)&sAl[row * LDST64 + c4 * 4] = lp;
        }
        // stage B: 64 k x 64 m hi/lo copy
#pragma unroll
        for (int i = 0; i < 2; i++) {
            const int idx = i * 256 + tid;
            const int row = idx >> 3;
            const int seg = idx & 7;
            const size_t src = (size_t)(k0 + row) * 256 + kb + seg * 8;
            *(uint4*)&sBh[row * LDST64 + seg * 8] = *(const uint4*)(Bhg + src);
            *(uint4*)&sBl[row * LDST64 + seg * 8] = *(const uint4*)(Blg + src);
        }
        __syncthreads();

        s16x8 ah[2][2], al[2][2], bh[2][2], bl[2][2];
#pragma unroll
        for (int nt = 0; nt < 2; nt++)
#pragma unroll
            for (int ks = 0; ks < 2; ks++) {
                const int off = (wr * 32 + nt * 16 + lr) * LDST64 + ks * 32 + lk * 8;
                ah[nt][ks] = *(const s16x8*)&sAh[off];
                al[nt][ks] = *(const s16x8*)&sAl[off];
            }
#pragma unroll
        for (int kt = 0; kt < 2; kt++)
#pragma unroll
            for (int ks = 0; ks < 2; ks++) {
                const int off = (wc * 32 + kt * 16 + lr) * LDST64 + ks * 32 + lk * 8;
                bh[kt][ks] = *(const s16x8*)&sBh[off];
                bl[kt][ks] = *(const s16x8*)&sBl[off];
            }
#pragma unroll
        for (int ks = 0; ks < 2; ks++)
#pragma unroll
            for (int nt = 0; nt < 2; nt++)
#pragma unroll
                for (int kt = 0; kt < 2; kt++) {
                    acc[nt][kt] = __builtin_amdgcn_mfma_f32_16x16x32_bf16(ah[nt][ks], bh[kt][ks], acc[nt][kt], 0, 0, 0);
                    acc[nt][kt] = __builtin_amdgcn_mfma_f32_16x16x32_bf16(ah[nt][ks], bl[kt][ks], acc[nt][kt], 0, 0, 0);
                    acc[nt][kt] = __builtin_amdgcn_mfma_f32_16x16x32_bf16(al[nt][ks], bh[kt][ks], acc[nt][kt], 0, 0, 0);
                }
        __syncthreads();
    }

    float* Og = Tout + ((size_t)g << 18);
#pragma unroll
    for (int kt = 0; kt < 2; kt++) {
        const int col = k0 + wc * 32 + kt * 16 + lr;
        const float inv = 1.0f / csum[g * 256 + col];
#pragma unroll
        for (int nt = 0; nt < 2; nt++) {
            const int rbase = n0 + wr * 32 + nt * 16 + lk * 4;
#pragma unroll
            for (int r = 0; r < 4; r++)
                Og[(size_t)(rbase + r) * 256 + col] = acc[nt][kt][r] * inv;
        }
    }
}

// ---------------- level 5: pair-product + normalized dot -----------------
__global__ void k_l5(const float* __restrict__ Tin, const float* __restrict__ a5,
                     float* __restrict__ out) {
    const int n = blockIdx.x;
    const int m = threadIdx.x;
    __shared__ float sv[256], sw[256];
    float w = sp10f(a5[m]);
    float v = Tin[(size_t)n * 256 + m] * Tin[(size_t)(N_PTS + n) * 256 + m] * w;
    sv[m] = v;
    sw[m] = w;
    __syncthreads();
    for (int s = 128; s > 0; s >>= 1) {
        if (m < s) { sv[m] += sv[m + s]; sw[m] += sw[m + s]; }
        __syncthreads();
    }
    if (m == 0) out[n] = sv[0] / sw[0];
}

extern "C" void kernel_launch(void* const* d_in, const int* in_sizes, int n_in,
                              void* d_out, int out_size, void* d_ws, size_t ws_size,
                              hipStream_t stream) {
    const float* X  = (const float*)d_in[0];
    const float* wf = (const float*)d_in[1];
    const float* wm = (const float*)d_in[2];
    const float* wl = (const float*)d_in[3];
    const float* b1 = (const float*)d_in[4];
    const float* bm = (const float*)d_in[5];
    const float* bl = (const float*)d_in[6];
    const float* af = (const float*)d_in[7];
    const float* am = (const float*)d_in[8];
    const float* a0 = (const float*)d_in[9];
    const float* a1 = (const float*)d_in[10];
    const float* a2 = (const float*)d_in[11];
    const float* a3 = (const float*)d_in[12];
    const float* a4 = (const float*)d_in[13];
    const float* a5 = (const float*)d_in[14];
    float* out = (float*)d_out;

    float* ws    = (float*)d_ws;
    float* Wpack = ws;                                 // 786432 f
    float* Xt    = Wpack + 786432;                     // 65536 f
    float* csum  = Xt + 65536;                         // 15872 f
    unsigned short* Anth = (unsigned short*)(csum + 15872);  // 62*65536 us
    unsigned short* Antl = Anth + (size_t)62 * 65536;        // 62*65536 us
    float* B0    = (float*)(Antl + (size_t)62 * 65536);      // 32*1024*256 f
    float* B1    = B0 + (size_t)32 * N_PTS * M_DIM;          // 32*1024*256 f
    // P0h/P0l alias the B1 region (consumed by L0 before L1 writes B1)
    unsigned short* P0h = (unsigned short*)B1;               // 32*1024*256 us
    unsigned short* P0l = P0h + (size_t)32 * N_PTS * M_DIM;  // 32*1024*256 us

    k_prep3<<<1072, 256, 0, stream>>>(X, wf, wm, wl, b1, bm, bl, af, am,
                                      a0, a1, a2, a3, a4, Wpack, Xt, Anth, Antl);
    k_csum_t<<<dim3(62, 64), 256, 0, stream>>>(Anth, Antl, csum);
    k_phase1<<<dim3(32, 8, 8), 512, 0, stream>>>(Xt, Wpack, P0h, P0l);

    // L0: presplit input, pure-copy staging, 64-tile BK=64
    k_g64ps<<<dim3(16, 4, 32), 256, 0, stream>>>(P0h, P0l, Anth, Antl, csum, B0);
    // L1-L4: 64-tile BK=64 paired (grids 1024/512/256/128)
    k_gemm64<<<dim3(16, 4, 16), 256, 0, stream>>>(B0, Anth + (size_t)32 * 65536,
                                                  Antl + (size_t)32 * 65536, csum + 32 * 256, B1);
    k_gemm64<<<dim3(16, 4, 8), 256, 0, stream>>>(B1, Anth + (size_t)48 * 65536,
                                                 Antl + (size_t)48 * 65536, csum + 48 * 256, B0);
    k_gemm64<<<dim3(16, 4, 4), 256, 0, stream>>>(B0, Anth + (size_t)56 * 65536,
                                                 Antl + (size_t)56 * 65536, csum + 56 * 256, B1);
    k_gemm64<<<dim3(16, 4, 2), 256, 0, stream>>>(B1, Anth + (size_t)60 * 65536,
                                                 Antl + (size_t)60 * 65536, csum + 60 * 256, B0);
    // level 5
    k_l5<<<N_PTS, 256, 0, stream>>>(B0, a5, out);
}

// Round 20
// 145.139 us; speedup vs baseline: 1.6098x; 1.0025x over previous
//
#include <hip/hip_runtime.h>
#include <cstdint>
#include <cstddef>

// Problem constants
#define D_DIM 64
#define M_DIM 256
#define N_PTS 1024

typedef __attribute__((ext_vector_type(4))) float f32x4;
typedef __attribute__((ext_vector_type(2))) float f32x2;
typedef __attribute__((ext_vector_type(8))) short s16x8;
typedef unsigned int u32;

// async global -> LDS direct copy, 16B per lane; LDS dest = wave-uniform
// base + lane*16 (pass the wave-uniform base); global src is per-lane.
static __device__ __forceinline__ void cp16(const unsigned short* g,
                                            unsigned short* l) {
    const __attribute__((address_space(1))) u32* gp =
        (const __attribute__((address_space(1))) u32*)g;
    __attribute__((address_space(3))) u32* lp =
        (__attribute__((address_space(3))) u32*)l;
    __builtin_amdgcn_global_load_lds(gp, lp, 16, 0, 0);
}

static __device__ __forceinline__ f32x2 pkfma(f32x2 a, f32x2 b, f32x2 c) {
#if __has_builtin(__builtin_elementwise_fma)
    return __builtin_elementwise_fma(a, b, c);
#else
    f32x2 r; r.x = fmaf(a.x, b.x, c.x); r.y = fmaf(a.y, b.y, c.y); return r;
#endif
}
static __device__ __forceinline__ f32x2 sp2(float s) {
    f32x2 r; r.x = s; r.y = s; return r;
}

static __device__ __forceinline__ float sp10f(float x) {
    // softplus(10x)/10, numerically stable, matches jax.nn.softplus
    float t = 10.f * x;
    return 0.1f * (fmaxf(t, 0.f) + log1pf(__expf(-fabsf(t))));
}

// packed branch-free tanh: 1 - 2/(exp2(x*2log2e)+1); single v_exp per lane
static __device__ __forceinline__ f32x2 ftanh2(f32x2 x) {
    f32x2 xs = x * sp2(2.88539008177793f);   // 2*log2(e)
    f32x2 e;
    e.x = __builtin_amdgcn_exp2f(xs.x);
    e.y = __builtin_amdgcn_exp2f(xs.y);
    f32x2 ep = e + sp2(1.f);
    f32x2 r;
    r.x = __builtin_amdgcn_rcpf(ep.x);
    r.y = __builtin_amdgcn_rcpf(ep.y);
    return pkfma(sp2(-2.f), r, sp2(1.f));
}

static __device__ __forceinline__ unsigned short f2bf(float x) {
    unsigned u = __float_as_uint(x);
    u = u + 0x7FFFu + ((u >> 16) & 1u);   // round-to-nearest-even
    return (unsigned short)(u >> 16);
}
static __device__ __forceinline__ float bf2f(unsigned short h) {
    return __uint_as_float(((unsigned)h) << 16);
}

// rne-hi / trunc-lo split of one fp32 -> (rounded-u32, lo-float-bits)
static __device__ __forceinline__ void split1(float x, unsigned& uh, unsigned& ul) {
    unsigned u = __float_as_uint(x);
    uh = u + 0x7FFFu + ((u >> 16) & 1u);               // rne in upper 16
    ul = __float_as_uint(x - __uint_as_float(uh & 0xFFFF0000u));  // exact tail
}

// map global level-group index g (0..61) -> (raw pointer, local g)
static __device__ __forceinline__ const float* map_g(int g, const float* a0, const float* a1,
                                                     const float* a2, const float* a3,
                                                     const float* a4, int& lg) {
    if (g < 32) { lg = g;      return a0; }
    if (g < 48) { lg = g - 32; return a1; }
    if (g < 56) { lg = g - 48; return a2; }
    if (g < 60) { lg = g - 56; return a3; }
    lg = g - 60; return a4;
}

// ---------------- fused prep: X-transpose + weight pack + HT transpose ---
__global__ __launch_bounds__(256) void k_prep3(
    const float* __restrict__ X, const float* __restrict__ wf,
    const float* __restrict__ wm, const float* __restrict__ wl,
    const float* __restrict__ b1, const float* __restrict__ bm,
    const float* __restrict__ bl, const float* __restrict__ af,
    const float* __restrict__ am,
    const float* __restrict__ a0, const float* __restrict__ a1,
    const float* __restrict__ a2, const float* __restrict__ a3,
    const float* __restrict__ a4,
    float* __restrict__ Wpack, float* __restrict__ Xt,
    unsigned short* __restrict__ Anth, unsigned short* __restrict__ Antl) {
    __shared__ float tile[64][65];
    const int t = threadIdx.x;
    const int b = blockIdx.x;
    if (b < 16) {
        const int n0 = b * 64;
#pragma unroll
        for (int i = 0; i < 4; i++) {
            const int f   = i * 256 + t;
            const int row = f >> 4;
            const int c4  = f & 15;
            float4 v = *(const float4*)(X + (size_t)(n0 + row) * 64 + c4 * 4);
            tile[row][c4 * 4 + 0] = v.x;
            tile[row][c4 * 4 + 1] = v.y;
            tile[row][c4 * 4 + 2] = v.z;
            tile[row][c4 * 4 + 3] = v.w;
        }
        __syncthreads();
#pragma unroll
        for (int i = 0; i < 4; i++) {
            const int f    = i * 256 + t;
            const int drow = f >> 4;
            const int c4   = f & 15;
            float4 v;
            v.x = tile[c4 * 4 + 0][drow];
            v.y = tile[c4 * 4 + 1][drow];
            v.z = tile[c4 * 4 + 2][drow];
            v.w = tile[c4 * 4 + 3][drow];
            *(float4*)(Xt + (size_t)drow * 1024 + n0 + c4 * 4) = v;
        }
        return;
    }
    if (b < 80) {
        const int id = (b - 16) * 256 + t;  // 0..16383
        float r[48];
#pragma unroll
        for (int q = 0; q < 48; q++) r[q] = 0.f;
#pragma unroll
        for (int q = 0; q < 3; q++) {
            r[0 + q] = sp10f(wf[id * 3 + q]);
            r[3 + q] = b1[id * 3 + q];
            r[6 + q] = tanhf(af[id * 3 + q]);
            r[39 + q] = sp10f(wl[id * 3 + q]);
        }
#pragma unroll
        for (int l = 0; l < 2; l++) {
            const size_t b9 = ((size_t)l * 16384 + id) * 9;
            const size_t b3 = ((size_t)l * 16384 + id) * 3;
#pragma unroll
            for (int q = 0; q < 9; q++) r[9 + l * 15 + q] = sp10f(wm[b9 + q]);
#pragma unroll
            for (int q = 0; q < 3; q++) {
                r[18 + l * 15 + q] = bm[b3 + q];
                r[21 + l * 15 + q] = tanhf(am[b3 + q]);
            }
        }
        r[42] = bl[id];
        float4* o = (float4*)(Wpack + (size_t)id * 48);
#pragma unroll
        for (int q = 0; q < 12; q++) o[q] = ((float4*)r)[q];
        return;
    }
    // HT transpose + sp10 + bf16 hi/lo split: An_t[g][k][m]
    const int idx = b - 80;
    const int g   = idx >> 4;
    const int rr  = idx & 15;
    const int m0  = (rr & 3) * 64;
    const int k0  = (rr >> 2) * 64;
    int lg;
    const float* A  = map_g(g, a0, a1, a2, a3, a4, lg);
    const float* Ag = A + (size_t)lg * 65536;

#pragma unroll
    for (int i = 0; i < 4; i++) {
        const int f   = i * 256 + t;
        const int row = f >> 4;
        const int c4  = f & 15;
        float4 v = *(const float4*)(Ag + (size_t)(m0 + row) * 256 + k0 + c4 * 4);
        tile[row][c4 * 4 + 0] = v.x;
        tile[row][c4 * 4 + 1] = v.y;
        tile[row][c4 * 4 + 2] = v.z;
        tile[row][c4 * 4 + 3] = v.w;
    }
    __syncthreads();

#pragma unroll
    for (int i = 0; i < 4; i++) {
        const int f    = i * 256 + t;
        const int krow = f >> 4;
        const int c4   = f & 15;
        float v0 = sp10f(tile[c4 * 4 + 0][krow]);
        float v1 = sp10f(tile[c4 * 4 + 1][krow]);
        float v2 = sp10f(tile[c4 * 4 + 2][krow]);
        float v3 = sp10f(tile[c4 * 4 + 3][krow]);
        unsigned short h0 = f2bf(v0), h1 = f2bf(v1), h2 = f2bf(v2), h3 = f2bf(v3);
        ushort4 hi, lo;
        hi.x = h0; hi.y = h1; hi.z = h2; hi.w = h3;
        lo.x = f2bf(v0 - bf2f(h0));
        lo.y = f2bf(v1 - bf2f(h1));
        lo.z = f2bf(v2 - bf2f(h2));
        lo.w = f2bf(v3 - bf2f(h3));
        const size_t dst = (size_t)g * 65536 + (size_t)(k0 + krow) * 256 + m0 + c4 * 4;
        *(ushort4*)(Anth + dst) = hi;
        *(ushort4*)(Antl + dst) = lo;
    }
}

// column sums (over m) from transposed hi/lo rows.
__global__ void k_csum_t(const unsigned short* __restrict__ Anth,
                         const unsigned short* __restrict__ Antl,
                         float* __restrict__ csum) {
    const int g    = blockIdx.x;
    const int w    = threadIdx.x >> 6;
    const int lane = threadIdx.x & 63;
    const int k    = blockIdx.y * 4 + w;
    const size_t base = (size_t)g * 65536 + k * 256 + lane * 4;
    uint2 vh = *(const uint2*)(Anth + base);
    uint2 vl = *(const uint2*)(Antl + base);
    float s = 0.f;
    s += bf2f((unsigned short)(vh.x & 0xFFFFu)) + bf2f((unsigned short)(vh.x >> 16));
    s += bf2f((unsigned short)(vh.y & 0xFFFFu)) + bf2f((unsigned short)(vh.y >> 16));
    s += bf2f((unsigned short)(vl.x & 0xFFFFu)) + bf2f((unsigned short)(vl.x >> 16));
    s += bf2f((unsigned short)(vl.y & 0xFFFFu)) + bf2f((unsigned short)(vl.y >> 16));
    for (int off = 32; off > 0; off >>= 1) s += __shfl_down(s, off);
    if (lane == 0) csum[g * 256 + k] = s;
}

// ---------------- phase 1: wave = one (d,m) chain, 2 n per lane (packed) -
__global__ __launch_bounds__(512, 1) void k_phase1(
    const float* __restrict__ Xt, const float* __restrict__ Wpack,
    unsigned short* __restrict__ P0h, unsigned short* __restrict__ P0l) {
    __shared__ float sT[128][33];
    __shared__ float sXd[2][128];
    const int j  = blockIdx.x;        // d-pair
    const int mc = blockIdx.y;        // m-chunk of 32
    const int n0 = blockIdx.z * 128;  // n base
    const int t  = threadIdx.x;
    const int w    = __builtin_amdgcn_readfirstlane(t >> 6);
    const int lane = t & 63;

    if (t < 256)
        sXd[t >> 7][t & 127] = Xt[(size_t)(2 * j + (t >> 7)) * 1024 + n0 + (t & 127)];
    __syncthreads();

    f32x2 xe0, xe1;
    xe0.x = sXd[0][lane]; xe0.y = sXd[0][64 + lane];
    xe1.x = sXd[1][lane]; xe1.y = sXd[1][64 + lane];

    const f32x2 one2 = sp2(1.f);
    f32x2 p0;

#pragma unroll 2
    for (int it = 0; it < 8; it++) {
        const int i  = it >> 1;
        const int e  = it & 1;
        const int mm = w * 4 + i;          // 0..31 within this m-chunk
        const int m  = mc * 32 + mm;       // global m
        const float* __restrict__ rp =
            Wpack + (size_t)(((2 * j + e) << 8) + m) * 48;
        float W1a[3], B1a[3], T1a[3], Wm[2][9], Bm[2][3], Tm[2][3], Wla[3];
#pragma unroll
        for (int r = 0; r < 3; r++) {
            W1a[r] = rp[r];
            B1a[r] = rp[3 + r];
            T1a[r] = rp[6 + r];
            Bm[0][r] = rp[18 + r];
            Tm[0][r] = rp[21 + r];
            Bm[1][r] = rp[33 + r];
            Tm[1][r] = rp[36 + r];
            Wla[r] = rp[39 + r];
        }
#pragma unroll
        for (int q = 0; q < 9; q++) {
            Wm[0][q] = rp[9 + q];
            Wm[1][q] = rp[24 + q];
        }
        const float Bla = rp[42];

        const f32x2 x = e ? xe1 : xe0;
        f32x2 phi[3], pd[3];
#pragma unroll
        for (int r = 0; r < 3; r++) {
            f32x2 z  = pkfma(x, sp2(W1a[r]), sp2(B1a[r]));
            f32x2 tz = ftanh2(z);
            f32x2 ta = sp2(T1a[r]);
            pd[r]  = sp2(W1a[r]) * pkfma(ta, pkfma(-tz, tz, one2), one2);
            phi[r] = pkfma(tz, ta, z);
        }
#pragma unroll
        for (int l = 0; l < 2; l++) {
            f32x2 nphi[3], npd[3];
#pragma unroll
            for (int q = 0; q < 3; q++) {
                f32x2 z  = sp2(Bm[l][q]);
                f32x2 dp = sp2(0.f);
#pragma unroll
                for (int r = 0; r < 3; r++) {
                    f32x2 wv = sp2(Wm[l][r * 3 + q]);
                    z  = pkfma(phi[r], wv, z);
                    dp = pkfma(pd[r],  wv, dp);
                }
                f32x2 tz = ftanh2(z);
                f32x2 ta = sp2(Tm[l][q]);
                nphi[q] = pkfma(tz, ta, z);
                npd[q]  = dp * pkfma(ta, pkfma(-tz, tz, one2), one2);
            }
#pragma unroll
            for (int q = 0; q < 3; q++) { phi[q] = nphi[q]; pd[q] = npd[q]; }
        }
        f32x2 z  = sp2(Bla);
        f32x2 dp = sp2(0.f);
#pragma unroll
        for (int r = 0; r < 3; r++) {
            f32x2 wv = sp2(Wla[r]);
            z  = pkfma(phi[r], wv, z);
            dp = pkfma(pd[r],  wv, dp);
        }
        // sigmoid via single exp2 per component
        f32x2 zs = z * sp2(-1.4426950408889634f);
        f32x2 s;
        s.x = __builtin_amdgcn_rcpf(1.f + __builtin_amdgcn_exp2f(zs.x));
        s.y = __builtin_amdgcn_rcpf(1.f + __builtin_amdgcn_exp2f(zs.y));
        f32x2 prod = dp * s * (one2 - s);
        if (e == 0) {
            p0 = prod;
        } else {
            sT[lane][mm]      = p0.x * prod.x;
            sT[64 + lane][mm] = p0.y * prod.y;
        }
    }
    __syncthreads();

    // cooperative coalesced write: sT (128 n x 32 m) -> P0h/P0l[j][n][m]
    const size_t base = ((size_t)j * N_PTS + n0) * M_DIM + mc * 32;
#pragma unroll
    for (int it = 0; it < 2; it++) {
        const int idx = it * 512 + t;   // 1024 float4 slots
        const int row = idx >> 3;       // n local 0..127
        const int c4  = idx & 7;        // m float4 (8 per row)
        float4 v;
        v.x = sT[row][c4 * 4 + 0];
        v.y = sT[row][c4 * 4 + 1];
        v.z = sT[row][c4 * 4 + 2];
        v.w = sT[row][c4 * 4 + 3];
        unsigned uh0, ul0, uh1, ul1, uh2, ul2, uh3, ul3;
        split1(v.x, uh0, ul0);
        split1(v.y, uh1, ul1);
        split1(v.z, uh2, ul2);
        split1(v.w, uh3, ul3);
        uint2 hp, lp;
        hp.x = __builtin_amdgcn_perm(uh1, uh0, 0x07060302u);
        hp.y = __builtin_amdgcn_perm(uh3, uh2, 0x07060302u);
        lp.x = __builtin_amdgcn_perm(ul1, ul0, 0x07060302u);
        lp.y = __builtin_amdgcn_perm(ul3, ul2, 0x07060302u);
        *(uint2*)(P0h + base + (size_t)row * M_DIM + c4 * 4) = hp;
        *(uint2*)(P0l + base + (size_t)row * M_DIM + c4 * 4) = lp;
    }
}

#define LDST64 72  // padded LDS row stride (bf16 elems) for ds_write paths

// ---------------- L0: 64x64 GEMM, BK=64, async direct-to-LDS staging -----
// All four buffers are pure copies -> global_load_lds (width 16), unpadded
// [64][64] LDS, XOR-swizzled global source (cslot = slot ^ (row&7)) so the
// swizzled fragment reads are ~conflict-free (2-way max).
__global__ __launch_bounds__(256, 4) void k_g64ps(
    const unsigned short* __restrict__ Th, const unsigned short* __restrict__ Tl,
    const unsigned short* __restrict__ Bh, const unsigned short* __restrict__ Bl,
    const float* __restrict__ csum, float* __restrict__ Tout) {
    __shared__ unsigned short sAh[64 * 64];
    __shared__ unsigned short sAl[64 * 64];
    __shared__ unsigned short sBh[64 * 64];
    __shared__ unsigned short sBl[64 * 64];

    const int g  = blockIdx.z;
    const int n0 = blockIdx.x * 64;
    const int k0 = blockIdx.y * 64;
    const unsigned short* Thg = Th + ((size_t)g << 18);
    const unsigned short* Tlg = Tl + ((size_t)g << 18);
    const unsigned short* Bhg = Bh + ((size_t)g << 16);
    const unsigned short* Blg = Bl + ((size_t)g << 16);

    const int tid  = threadIdx.x;
    const int lane = tid & 63;
    const int w    = tid >> 6;
    const int wr   = w >> 1;
    const int wc   = w & 1;
    const int lr   = lane & 15;
    const int lk   = lane >> 4;

    f32x4 acc[2][2];
#pragma unroll
    for (int a = 0; a < 2; a++)
#pragma unroll
        for (int b = 0; b < 2; b++) acc[a][b] = (f32x4){0.f, 0.f, 0.f, 0.f};

    for (int kb = 0; kb < 256; kb += 64) {
        // async staging: issue i covers idx = i*256 + tid (16B slots)
#pragma unroll
        for (int i = 0; i < 2; i++) {
            const int idx      = i * 256 + tid;
            const int idx_base = i * 256 + (w << 6);   // wave-uniform
            const int row  = idx >> 3;
            const int slot = idx & 7;
            const int cslot = slot ^ (row & 7);        // pre-swizzled source
            const size_t srcA = (size_t)(n0 + row) * 256 + kb + cslot * 8;
            const size_t srcB = (size_t)(k0 + row) * 256 + kb + cslot * 8;
            cp16(Thg + srcA, sAh + (size_t)idx_base * 8);
            cp16(Tlg + srcA, sAl + (size_t)idx_base * 8);
            cp16(Bhg + srcB, sBh + (size_t)idx_base * 8);
            cp16(Blg + srcB, sBl + (size_t)idx_base * 8);
        }
        __syncthreads();

        s16x8 ah[2][2], al[2][2], bh[2][2], bl[2][2];
#pragma unroll
        for (int nt = 0; nt < 2; nt++)
#pragma unroll
            for (int ks = 0; ks < 2; ks++) {
                const int row = wr * 32 + nt * 16 + lr;
                const int cs  = (ks * 4 + lk) ^ (row & 7);
                const int off = row * 64 + cs * 8;
                ah[nt][ks] = *(const s16x8*)&sAh[off];
                al[nt][ks] = *(const s16x8*)&sAl[off];
            }
#pragma unroll
        for (int kt = 0; kt < 2; kt++)
#pragma unroll
            for (int ks = 0; ks < 2; ks++) {
                const int row = wc * 32 + kt * 16 + lr;
                const int cs  = (ks * 4 + lk) ^ (row & 7);
                const int off = row * 64 + cs * 8;
                bh[kt][ks] = *(const s16x8*)&sBh[off];
                bl[kt][ks] = *(const s16x8*)&sBl[off];
            }
#pragma unroll
        for (int ks = 0; ks < 2; ks++)
#pragma unroll
            for (int nt = 0; nt < 2; nt++)
#pragma unroll
                for (int kt = 0; kt < 2; kt++) {
                    acc[nt][kt] = __builtin_amdgcn_mfma_f32_16x16x32_bf16(ah[nt][ks], bh[kt][ks], acc[nt][kt], 0, 0, 0);
                    acc[nt][kt] = __builtin_amdgcn_mfma_f32_16x16x32_bf16(ah[nt][ks], bl[kt][ks], acc[nt][kt], 0, 0, 0);
                    acc[nt][kt] = __builtin_amdgcn_mfma_f32_16x16x32_bf16(al[nt][ks], bh[kt][ks], acc[nt][kt], 0, 0, 0);
                }
        __syncthreads();
    }

    float* Og = Tout + ((size_t)g << 18);
#pragma unroll
    for (int kt = 0; kt < 2; kt++) {
        const int col = k0 + wc * 32 + kt * 16 + lr;
        const float inv = 1.0f / csum[g * 256 + col];
#pragma unroll
        for (int nt = 0; nt < 2; nt++) {
            const int rbase = n0 + wr * 32 + nt * 16 + lk * 4;
#pragma unroll
            for (int r = 0; r < 4; r++)
                Og[(size_t)(rbase + r) * 256 + col] = acc[nt][kt][r] * inv;
        }
    }
}

// ---------------- L1-L4: 64x64-tile, BK=64, paired GEMM ------------------
// A-side: fp32 pair-product + trunc split via ds_write (padded LDS).
// B-side: pure copy -> async global_load_lds (unpadded, XOR-swizzled).
__global__ __launch_bounds__(256, 4) void k_gemm64(const float* __restrict__ Tin,
                                                   const unsigned short* __restrict__ Bh,
                                                   const unsigned short* __restrict__ Bl,
                                                   const float* __restrict__ csum,
                                                   float* __restrict__ Tout) {
    __shared__ unsigned short sAh[64 * LDST64];
    __shared__ unsigned short sAl[64 * LDST64];
    __shared__ unsigned short sBh[64 * 64];
    __shared__ unsigned short sBl[64 * 64];

    const int g  = blockIdx.z;
    const int n0 = blockIdx.x * 64;
    const int k0 = blockIdx.y * 64;
    const float* T0  = Tin + (size_t)(2 * g) * N_PTS * 256;
    const float* T1p = T0 + (size_t)N_PTS * 256;
    const unsigned short* Bhg = Bh + ((size_t)g << 16);
    const unsigned short* Blg = Bl + ((size_t)g << 16);

    const int tid  = threadIdx.x;
    const int lane = tid & 63;
    const int w    = tid >> 6;
    const int wr   = w >> 1;
    const int wc   = w & 1;
    const int lr   = lane & 15;
    const int lk   = lane >> 4;

    f32x4 acc[2][2];
#pragma unroll
    for (int a = 0; a < 2; a++)
#pragma unroll
        for (int b = 0; b < 2; b++) acc[a][b] = (f32x4){0.f, 0.f, 0.f, 0.f};

    for (int kb = 0; kb < 256; kb += 64) {
        // stage B (async, swizzled source)
#pragma unroll
        for (int i = 0; i < 2; i++) {
            const int idx      = i * 256 + tid;
            const int idx_base = i * 256 + (w << 6);
            const int row  = idx >> 3;
            const int slot = idx & 7;
            const int cslot = slot ^ (row & 7);
            const size_t srcB = (size_t)(k0 + row) * 256 + kb + cslot * 8;
            cp16(Bhg + srcB, sBh + (size_t)idx_base * 8);
            cp16(Blg + srcB, sBl + (size_t)idx_base * 8);
        }
        // stage A: 64 n x 64 m fp32 pair-product -> trunc split hi/lo
#pragma unroll
        for (int i = 0; i < 4; i++) {
            const int idx = i * 256 + tid;   // 1024 float4 slots
            const int row = idx >> 4;        // 0..63
            const int c4  = idx & 15;        // 16 float4 per row
            float4 v = *(const float4*)(T0 + (size_t)(n0 + row) * 256 + kb + c4 * 4);
            float4 u = *(const float4*)(T1p + (size_t)(n0 + row) * 256 + kb + c4 * 4);
            v.x *= u.x; v.y *= u.y; v.z *= u.z; v.w *= u.w;
            const unsigned b0 = __float_as_uint(v.x);
            const unsigned b1 = __float_as_uint(v.y);
            const unsigned b2 = __float_as_uint(v.z);
            const unsigned b3 = __float_as_uint(v.w);
            uint2 hp, lp;
            hp.x = __builtin_amdgcn_perm(b1, b0, 0x07060302u);
            hp.y = __builtin_amdgcn_perm(b3, b2, 0x07060302u);
            const float l0 = v.x - __uint_as_float(b0 & 0xFFFF0000u);
            const float l1 = v.y - __uint_as_float(b1 & 0xFFFF0000u);
            const float l2 = v.z - __uint_as_float(b2 & 0xFFFF0000u);
            const float l3 = v.w - __uint_as_float(b3 & 0xFFFF0000u);
            lp.x = __builtin_amdgcn_perm(__float_as_uint(l1), __float_as_uint(l0), 0x07060302u);
            lp.y = __builtin_amdgcn_perm(__float_as_uint(l3), __float_as_uint(l2), 0x07060302u);
            *(uint2*)&sAh[row * LDST64 + c4 * 4] = hp;
            *(uint2*)&sAl[row * LDST64 + c4 * 4] = lp;
        }
        __syncthreads();

        s16x8 ah[2][2], al[2][2], bh[2][2], bl[2][2];
#pragma unroll
        for (int nt = 0; nt < 2; nt++)
#pragma unroll
            for (int ks = 0; ks < 2; ks++) {
                const int off = (wr * 32 + nt * 16 + lr) * LDST64 + ks * 32 + lk * 8;
                ah[nt][ks] = *(const s16x8*)&sAh[off];
                al[nt][ks] = *(const s16x8*)&sAl[off];
            }
#pragma unroll
        for (int kt = 0; kt < 2; kt++)
#pragma unroll
            for (int ks = 0; ks < 2; ks++) {
                const int row = wc * 32 + kt * 16 + lr;
                const int cs  = (ks * 4 + lk) ^ (row & 7);
                const int off = row * 64 + cs * 8;
                bh[kt][ks] = *(const s16x8*)&sBh[off];
                bl[kt][ks] = *(const s16x8*)&sBl[off];
            }
#pragma unroll
        for (int ks = 0; ks < 2; ks++)
#pragma unroll
            for (int nt = 0; nt < 2; nt++)
#pragma unroll
                for (int kt = 0; kt < 2; kt++) {
                    acc[nt][kt] = __builtin_amdgcn_mfma_f32_16x16x32_bf16(ah[nt][ks], bh[kt][ks], acc[nt][kt], 0, 0, 0);
                    acc[nt][kt] = __builtin_amdgcn_mfma_f32_16x16x32_bf16(ah[nt][ks], bl[kt][ks], acc[nt][kt], 0, 0, 0);
                    acc[nt][kt] = __builtin_amdgcn_mfma_f32_16x16x32_bf16(al[nt][ks], bh[kt][ks], acc[nt][kt], 0, 0, 0);
                }
        __syncthreads();
    }

    float* Og = Tout + ((size_t)g << 18);
#pragma unroll
    for (int kt = 0; kt < 2; kt++) {
        const int col = k0 + wc * 32 + kt * 16 + lr;
        const float inv = 1.0f / csum[g * 256 + col];
#pragma unroll
        for (int nt = 0; nt < 2; nt++) {
            const int rbase = n0 + wr * 32 + nt * 16 + lk * 4;
#pragma unroll
            for (int r = 0; r < 4; r++)
                Og[(size_t)(rbase + r) * 256 + col] = acc[nt][kt][r] * inv;
        }
    }
}

// ---------------- level 5: pair-product + normalized dot -----------------
__global__ void k_l5(const float* __restrict__ Tin, const float* __restrict__ a5,
                     float* __restrict__ out) {
    const int n = blockIdx.x;
    const int m = threadIdx.x;
    __shared__ float sv[256], sw[256];
    float w = sp10f(a5[m]);
    float v = Tin[(size_t)n * 256 + m] * Tin[(size_t)(N_PTS + n) * 256 + m] * w;
    sv[m] = v;
    sw[m] = w;
    __syncthreads();
    for (int s = 128; s > 0; s >>= 1) {
        if (m < s) { sv[m] += sv[m + s]; sw[m] += sw[m + s]; }
        __syncthreads();
    }
    if (m == 0) out[n] = sv[0] / sw[0];
}

extern "C" void kernel_launch(void* const* d_in, const int* in_sizes, int n_in,
                              void* d_out, int out_size, void* d_ws, size_t ws_size,
                              hipStream_t stream) {
    const float* X  = (const float*)d_in[0];
    const float* wf = (const float*)d_in[1];
    const float* wm = (const float*)d_in[2];
    const float* wl = (const float*)d_in[3];
    const float* b1 = (const float*)d_in[4];
    const float* bm = (const float*)d_in[5];
    const float* bl = (const float*)d_in[6];
    const float* af = (const float*)d_in[7];
    const float* am = (const float*)d_in[8];
    const float* a0 = (const float*)d_in[9];
    const float* a1 = (const float*)d_in[10];
    const float* a2 = (const float*)d_in[11];
    const float* a3 = (const float*)d_in[12];
    const float* a4 = (const float*)d_in[13];
    const float* a5 = (const float*)d_in[14];
    float* out = (float*)d_out;

    float* ws    = (float*)d_ws;
    float* Wpack = ws;                                 // 786432 f
    float* Xt    = Wpack + 786432;                     // 65536 f
    float* csum  = Xt + 65536;                         // 15872 f
    unsigned short* Anth = (unsigned short*)(csum + 15872);  // 62*65536 us
    unsigned short* Antl = Anth + (size_t)62 * 65536;        // 62*65536 us
    float* B0    = (float*)(Antl + (size_t)62 * 65536);      // 32*1024*256 f
    float* B1    = B0 + (size_t)32 * N_PTS * M_DIM;          // 32*1024*256 f
    // P0h/P0l alias the B1 region (consumed by L0 before L1 writes B1)
    unsigned short* P0h = (unsigned short*)B1;               // 32*1024*256 us
    unsigned short* P0l = P0h + (size_t)32 * N_PTS * M_DIM;  // 32*1024*256 us

    k_prep3<<<1072, 256, 0, stream>>>(X, wf, wm, wl, b1, bm, bl, af, am,
                                      a0, a1, a2, a3, a4, Wpack, Xt, Anth, Antl);
    k_csum_t<<<dim3(62, 64), 256, 0, stream>>>(Anth, Antl, csum);
    k_phase1<<<dim3(32, 8, 8), 512, 0, stream>>>(Xt, Wpack, P0h, P0l);

    // L0: presplit input, async pure-copy staging, 64-tile BK=64
    k_g64ps<<<dim3(16, 4, 32), 256, 0, stream>>>(P0h, P0l, Anth, Antl, csum, B0);
    // L1-L4: 64-tile BK=64 paired (grids 1024/512/256/128)
    k_gemm64<<<dim3(16, 4, 16), 256, 0, stream>>>(B0, Anth + (size_t)32 * 65536,
                                                  Antl + (size_t)32 * 65536, csum + 32 * 256, B1);
    k_gemm64<<<dim3(16, 4, 8), 256, 0, stream>>>(B1, Anth + (size_t)48 * 65536,
                                                 Antl + (size_t)48 * 65536, csum + 48 * 256, B0);
    k_gemm64<<<dim3(16, 4, 4), 256, 0, stream>>>(B0, Anth + (size_t)56 * 65536,
                                                 Antl + (size_t)56 * 65536, csum + 56 * 256, B1);
    k_gemm64<<<dim3(16, 4, 2), 256, 0, stream>>>(B1, Anth + (size_t)60 * 65536,
                                                 Antl + (size_t)60 * 65536, csum + 60 * 256, B0);
    // level 5
    k_l5<<<N_PTS, 256, 0, stream>>>(B0, a5, out);
}